// Round 4
// baseline (1002.979 us; speedup 1.0000x reference)
//
#include <hip/hip_runtime.h>

#define N_NODES 50000
#define E_EDGES 800000
#define IN_F    128
#define H_F     64
#define STD_EPS 1e-5f
#define BN_EPS  1e-5f

// ---------------------------------------------------------------- degree hist
__global__ __launch_bounds__(256) void k_hist(const int* __restrict__ dst,
                                              int* __restrict__ deg) {
  int e = blockIdx.x * 256 + threadIdx.x;
  if (e < E_EDGES) atomicAdd(&deg[dst[e]], 1);
}

// ------------------------------------------------------- sum of log(deg+1)
__global__ __launch_bounds__(256) void k_sumlog(const int* __restrict__ deg,
                                                float* __restrict__ scalars) {
  __shared__ float red[256];
  int i = blockIdx.x * 256 + threadIdx.x;
  float v = 0.f;
  if (i < N_NODES) v = logf((float)deg[i] + 1.0f);
  red[threadIdx.x] = v; __syncthreads();
  for (int s = 128; s > 0; s >>= 1) {
    if (threadIdx.x < s) red[threadIdx.x] += red[threadIdx.x + s];
    __syncthreads();
  }
  if (threadIdx.x == 0) atomicAdd(&scalars[0], red[0]);
}

// ------------------------------------------------------------- scan (3-phase)
__global__ __launch_bounds__(256) void k_scan_part(const int* __restrict__ deg,
                                                   int* __restrict__ partials) {
  __shared__ int red[256];
  int base = blockIdx.x * 1024;
  int s = 0;
  for (int j = threadIdx.x; j < 1024; j += 256) {
    int i = base + j;
    if (i < N_NODES) s += deg[i];
  }
  red[threadIdx.x] = s; __syncthreads();
  for (int st = 128; st > 0; st >>= 1) {
    if (threadIdx.x < st) red[threadIdx.x] += red[threadIdx.x + st];
    __syncthreads();
  }
  if (threadIdx.x == 0) partials[blockIdx.x] = red[0];
}

__global__ void k_scan_mid(int* __restrict__ partials, int nblk,
                           float* __restrict__ scalars) {
  if (threadIdx.x == 0) {
    int run = 0;
    for (int b = 0; b < nblk; b++) { int v = partials[b]; partials[b] = run; run += v; }
    scalars[1] = scalars[0] / (float)N_NODES;   // avg_log
  }
}

__global__ __launch_bounds__(256) void k_scan_final(const int* __restrict__ deg,
                                                    const int* __restrict__ partials,
                                                    int* __restrict__ row_ptr,
                                                    int* __restrict__ cursor) {
  __shared__ int ts[256];
  int base = blockIdx.x * 1024 + threadIdx.x * 4;
  int d[4]; int s = 0;
#pragma unroll
  for (int j = 0; j < 4; j++) {
    int i = base + j;
    d[j] = (i < N_NODES) ? deg[i] : 0;
    s += d[j];
  }
  ts[threadIdx.x] = s; __syncthreads();
  for (int off = 1; off < 256; off <<= 1) {
    int t = (threadIdx.x >= off) ? ts[threadIdx.x - off] : 0;
    __syncthreads();
    ts[threadIdx.x] += t;
    __syncthreads();
  }
  int excl = (threadIdx.x > 0) ? ts[threadIdx.x - 1] : 0;
  int run = partials[blockIdx.x] + excl;
#pragma unroll
  for (int j = 0; j < 4; j++) {
    int i = base + j;
    if (i < N_NODES) { row_ptr[i] = run; cursor[i] = run; run += d[j]; }
  }
  if (blockIdx.x == 0 && threadIdx.x == 0) row_ptr[N_NODES] = E_EDGES;
}

// ------------------------------------------------------------------- scatter
__global__ __launch_bounds__(256) void k_scatter(const int* __restrict__ src,
                                                 const int* __restrict__ dst,
                                                 int* __restrict__ cursor,
                                                 int* __restrict__ csr_src) {
  int e = blockIdx.x * 256 + threadIdx.x;
  if (e < E_EDGES) {
    int d = dst[e];
    int p = atomicAdd(&cursor[d], 1);
    csr_src[p] = src[e];
  }
}

// ---------------------------------------------------------- weight transpose
// postWT[layer][t][g][f832] ;  linWT[layer][col][row]
__global__ __launch_bounds__(256) void k_transpose(const float* __restrict__ pW1,
                                                   const float* __restrict__ pW2,
                                                   const float* __restrict__ lW1,
                                                   const float* __restrict__ lW2,
                                                   float* __restrict__ pWT,
                                                   float* __restrict__ lWT) {
  int idx = blockIdx.x * 256 + threadIdx.x;
  if (idx < 106496) {                       // 2 layers x 2 towers x 832 x 32
    int layer = idx / 53248, r = idx % 53248;
    int t = r / 26624, r2 = r % 26624;
    int f = r2 / 32, g = r2 % 32;
    const float* srcp = layer ? pW2 : pW1;
    pWT[(size_t)layer * 53248 + (size_t)(t * 32 + g) * 832 + f] =
        srcp[(size_t)t * 26624 + f * 32 + g];
  } else if (idx < 114688) {
    int j = idx - 106496;
    int layer = j / 4096, r2 = j % 4096;
    int row = r2 / 64, c = r2 % 64;
    const float* srcl = layer ? lW2 : lW1;
    lWT[(size_t)layer * 4096 + c * 64 + row] = srcl[row * 64 + c];
  }
}

// --------------------------------------------------------------------- embed
__global__ __launch_bounds__(256) void k_embed(const float* __restrict__ x,
                                               const float* __restrict__ W,
                                               const float* __restrict__ bias,
                                               float* __restrict__ h) {
  __shared__ float sW[IN_F * 64];    // 32 KB
  __shared__ float sx[IN_F * 20];    // x_T[k][16+pad4]
  for (int i = threadIdx.x; i < IN_F * 64; i += 256) sW[i] = W[i];
  int j = threadIdx.x & 63, ng = threadIdx.x >> 6;
  float bj = bias[j];
  for (int grp = blockIdx.x; grp < N_NODES / 16; grp += gridDim.x) {
    int n0 = grp * 16;
    __syncthreads();
    for (int idx = threadIdx.x; idx < 16 * IN_F; idx += 256) {
      int nl = idx >> 7, k = idx & 127;
      sx[k * 20 + nl] = x[(size_t)(n0 + nl) * IN_F + k];
    }
    __syncthreads();
    float a0 = bj, a1 = bj, a2 = bj, a3 = bj;
    const float* xp = &sx[ng * 4];
#pragma unroll 4
    for (int k = 0; k < IN_F; k++) {
      float4 xv = *(const float4*)&xp[k * 20];
      float w = sW[k * 64 + j];
      a0 = fmaf(xv.x, w, a0); a1 = fmaf(xv.y, w, a1);
      a2 = fmaf(xv.z, w, a2); a3 = fmaf(xv.w, w, a3);
    }
    size_t ob = (size_t)(n0 + ng * 4) * 64 + j;
    h[ob] = a0; h[ob + 64] = a1; h[ob + 128] = a2; h[ob + 192] = a3;
  }
}

// ------------------------------------------------------------------ pre A/B
// One TOWER per block (t = blockIdx.x & 1): LDS 32KB -> 4 blocks/CU.
template <bool BN>
__global__ __launch_bounds__(256) void k_preab(const float* __restrict__ hin,
                                               const float* __restrict__ preW,
                                               const float* __restrict__ preb,
                                               const float* __restrict__ bnscale,
                                               const float* __restrict__ bnshift,
                                               float* __restrict__ h2out,
                                               float* __restrict__ hA,
                                               float* __restrict__ hB) {
  __shared__ float sW[128 * 64];   // 32 KB (this tower)
  __shared__ float sh[64 * 20];    // h_T[k][16+pad4]
  int t = blockIdx.x & 1;
  const float* Wsrc = preW + (size_t)t * 128 * 64;
  for (int i = threadIdx.x; i < 128 * 64; i += 256) sW[i] = Wsrc[i];
  int f = threadIdx.x & 63, ng = threadIdx.x >> 6;   // ng in 0..3 -> 4 nodes each
  float pb = preb[t * 64 + f];
  const float* wA = &sW[f];
  const float* wB = &sW[64 * 64 + f];
  int nblk2 = gridDim.x >> 1;
  for (int grp = blockIdx.x >> 1; grp < N_NODES / 16; grp += nblk2) {
    int n0 = grp * 16;
    __syncthreads();
    for (int idx = threadIdx.x; idx < 16 * 64; idx += 256) {
      int nl = idx >> 6, k = idx & 63;
      float v = hin[(size_t)(n0 + nl) * 64 + k];
      if (BN) {
        v = fmaxf(fmaf(v, bnscale[k], bnshift[k]), 0.f);
        if (t == 0) h2out[(size_t)(n0 + nl) * 64 + k] = v;
      }
      sh[k * 20 + nl] = v;
    }
    __syncthreads();
    float a0 = pb, a1 = pb, a2 = pb, a3 = pb;
    float b0 = 0, b1 = 0, b2 = 0, b3 = 0;
    const float* hp = &sh[ng * 4];
#pragma unroll 4
    for (int k = 0; k < 64; k++) {
      float4 hv = *(const float4*)&hp[k * 20];
      float wa = wA[k * 64], wb = wB[k * 64];
      a0 = fmaf(hv.x, wa, a0); a1 = fmaf(hv.y, wa, a1);
      a2 = fmaf(hv.z, wa, a2); a3 = fmaf(hv.w, wa, a3);
      b0 = fmaf(hv.x, wb, b0); b1 = fmaf(hv.y, wb, b1);
      b2 = fmaf(hv.z, wb, b2); b3 = fmaf(hv.w, wb, b3);
    }
    size_t nb = (size_t)(n0 + ng * 4);
    int tf = t * 64 + f;
    hA[nb * 128 + tf] = a0;          hB[nb * 128 + tf] = b0;
    hA[(nb + 1) * 128 + tf] = a1;    hB[(nb + 1) * 128 + tf] = b1;
    hA[(nb + 2) * 128 + tf] = a2;    hB[(nb + 2) * 128 + tf] = b2;
    hA[(nb + 3) * 128 + tf] = a3;    hB[(nb + 3) * 128 + tf] = b3;
  }
}

// --------------------------------------------------- fused conv main kernel
// 8 nodes/block, 4 waves; wave handles 2 nodes' aggregation sequentially.
// LDS stores only the 5 UNIQUE feature slices [t][feat5][node8][hf64] (20KB);
// the x1/xSA/xSB expansion is factored into 3 accumulators G1,G2,G3 per
// (node,g), combined as G1 + sA*G2 + sB*G3 at the end.
// Weights read from transposed postWT[t][g][f832] as dwordx4.
__global__ __launch_bounds__(256, 5) void k_conv(const float* __restrict__ hA,
                                                 const float* __restrict__ hB,
                                                 const float* __restrict__ hskip,
                                                 const int* __restrict__ row_ptr,
                                                 const int* __restrict__ csr_src,
                                                 const float* __restrict__ postWT,
                                                 const float* __restrict__ postb,
                                                 const float* __restrict__ linWT,
                                                 const float* __restrict__ linb,
                                                 const float* __restrict__ scalars,
                                                 float* __restrict__ out) {
  __shared__ float sm[2 * 5 * 8 * 64];   // 20480 B; [(t*5+feat)*512 + node*64 + hf]
  __shared__ float sAB[16];              // sA[0..7], sB[8..15]
  int w = threadIdx.x >> 6, lane = threadIdx.x & 63;
  int n0 = blockIdx.x * 8;
  int t = lane >> 5, fb = (lane & 31) * 2;
  int off = t * 64 + fb;
  float avg = scalars[1];

  // ---- phase A: aggregation, 2 nodes per wave, 4 loads in flight
#pragma unroll 1
  for (int k = 0; k < 2; k++) {
    int nl = w * 2 + k;
    int n = n0 + nl;
    float2 a = *(const float2*)&hA[(size_t)n * 128 + off];
    int rp0 = __builtin_amdgcn_readfirstlane(row_ptr[n]);
    int rp1 = __builtin_amdgcn_readfirstlane(row_ptr[n + 1]);
    float sx0=0,sy0=0,qx0=0,qy0=0, sx1=0,sy1=0,qx1=0,qy1=0;
    float mnx0=INFINITY,mny0=INFINITY,mxx0=-INFINITY,mxy0=-INFINITY;
    float mnx1=INFINITY,mny1=INFINITY,mxx1=-INFINITY,mxy1=-INFINITY;
    int i = rp0;
    int end4 = rp0 + ((rp1 - rp0) & ~3);
    if (i < end4) {
      int s0 = csr_src[i], s1 = csr_src[i+1], s2 = csr_src[i+2], s3 = csr_src[i+3];
      while (true) {
        float2 v0 = *(const float2*)&hB[(size_t)s0 * 128 + off];
        float2 v1 = *(const float2*)&hB[(size_t)s1 * 128 + off];
        float2 v2 = *(const float2*)&hB[(size_t)s2 * 128 + off];
        float2 v3 = *(const float2*)&hB[(size_t)s3 * 128 + off];
        i += 4;
        bool more = (i < end4);
        if (more) { s0 = csr_src[i]; s1 = csr_src[i+1]; s2 = csr_src[i+2]; s3 = csr_src[i+3]; }
        float e0x = v0.x + a.x, e0y = v0.y + a.y;
        float e1x = v1.x + a.x, e1y = v1.y + a.y;
        float e2x = v2.x + a.x, e2y = v2.y + a.y;
        float e3x = v3.x + a.x, e3y = v3.y + a.y;
        sx0 += e0x; qx0 = fmaf(e0x,e0x,qx0); mnx0 = fminf(mnx0,e0x); mxx0 = fmaxf(mxx0,e0x);
        sy0 += e0y; qy0 = fmaf(e0y,e0y,qy0); mny0 = fminf(mny0,e0y); mxy0 = fmaxf(mxy0,e0y);
        sx1 += e1x; qx1 = fmaf(e1x,e1x,qx1); mnx1 = fminf(mnx1,e1x); mxx1 = fmaxf(mxx1,e1x);
        sy1 += e1y; qy1 = fmaf(e1y,e1y,qy1); mny1 = fminf(mny1,e1y); mxy1 = fmaxf(mxy1,e1y);
        sx0 += e2x; qx0 = fmaf(e2x,e2x,qx0); mnx0 = fminf(mnx0,e2x); mxx0 = fmaxf(mxx0,e2x);
        sy0 += e2y; qy0 = fmaf(e2y,e2y,qy0); mny0 = fminf(mny0,e2y); mxy0 = fmaxf(mxy0,e2y);
        sx1 += e3x; qx1 = fmaf(e3x,e3x,qx1); mnx1 = fminf(mnx1,e3x); mxx1 = fmaxf(mxx1,e3x);
        sy1 += e3y; qy1 = fmaf(e3y,e3y,qy1); mny1 = fminf(mny1,e3y); mxy1 = fmaxf(mxy1,e3y);
        if (!more) break;
      }
    }
    {   // masked tail: 0..3 edges, all loads issued together
      int r = rp1 - i;
      if (r > 0) {
        int e1i = (r > 1) ? i + 1 : i;
        int e2i = (r > 2) ? i + 2 : i;
        int t0 = csr_src[i], t1 = csr_src[e1i], t2 = csr_src[e2i];
        float2 u0 = *(const float2*)&hB[(size_t)t0 * 128 + off];
        float2 u1 = *(const float2*)&hB[(size_t)t1 * 128 + off];
        float2 u2 = *(const float2*)&hB[(size_t)t2 * 128 + off];
        float ex = u0.x + a.x, ey = u0.y + a.y;
        sx0 += ex; qx0 = fmaf(ex,ex,qx0); mnx0 = fminf(mnx0,ex); mxx0 = fmaxf(mxx0,ex);
        sy0 += ey; qy0 = fmaf(ey,ey,qy0); mny0 = fminf(mny0,ey); mxy0 = fmaxf(mxy0,ey);
        if (r > 1) {
          ex = u1.x + a.x; ey = u1.y + a.y;
          sx1 += ex; qx1 = fmaf(ex,ex,qx1); mnx1 = fminf(mnx1,ex); mxx1 = fmaxf(mxx1,ex);
          sy1 += ey; qy1 = fmaf(ey,ey,qy1); mny1 = fminf(mny1,ey); mxy1 = fmaxf(mxy1,ey);
        }
        if (r > 2) {
          ex = u2.x + a.x; ey = u2.y + a.y;
          sx0 += ex; qx0 = fmaf(ex,ex,qx0); mnx0 = fminf(mnx0,ex); mxx0 = fmaxf(mxx0,ex);
          sy0 += ey; qy0 = fmaf(ey,ey,qy0); mny0 = fminf(mny0,ey); mxy0 = fmaxf(mxy0,ey);
        }
      }
    }
    int dg = rp1 - rp0;
    float cnt = (float)(dg > 0 ? dg : 1);
    float inv = 1.0f / cnt;
    float meanx = (sx0 + sx1) * inv, meany = (sy0 + sy1) * inv;
    float qx = qx0 + qx1, qy = qy0 + qy1;
    float sdx = sqrtf(fmaxf(qx * inv - meanx * meanx, 0.f) + STD_EPS);
    float sdy = sqrtf(fmaxf(qy * inv - meany * meany, 0.f) + STD_EPS);
    float mnx = fminf(mnx0, mnx1), mny = fminf(mny0, mny1);
    float mxx = fmaxf(mxx0, mxx1), mxy = fmaxf(mxy0, mxy1);
    if (dg == 0) { mnx = 0; mny = 0; mxx = 0; mxy = 0; }
    float ldv = logf(cnt + 1.f);
    float2 hsv = *(const float2*)&hskip[(size_t)n * 64 + fb];
    // write 5 unique slices
    float* bp = &sm[t * 2560 + nl * 64 + fb];
    *(float2*)&bp[0]    = hsv;
    *(float2*)&bp[512]  = make_float2(meanx, meany);
    *(float2*)&bp[1024] = make_float2(mnx, mny);
    *(float2*)&bp[1536] = make_float2(mxx, mxy);
    *(float2*)&bp[2048] = make_float2(sdx, sdy);
    if (lane == 0) { sAB[nl] = ldv / avg; sAB[8 + nl] = avg / ldv; }
  }
  __syncthreads();

  // ---- phase C: factored post matmul; wave w covers hf [w*16, w*16+16)
  float g1[8] = {0,0,0,0,0,0,0,0};
  float g2[8] = {0,0,0,0,0,0,0,0};
  float g3[8] = {0,0,0,0,0,0,0,0};
  {
    int g = lane & 31, hf0 = w * 16;
    const float* wbase = &postWT[(size_t)(t * 32 + g) * 832 + hf0];
    const float* vb = &sm[t * 2560 + hf0];
    // h part (f13 block 0): into g1
#pragma unroll
    for (int j = 0; j < 16; j += 4) {
      float4 wh = *(const float4*)&wbase[j];
#pragma unroll
      for (int nn = 0; nn < 8; nn++) {
        float4 v = *(const float4*)&vb[nn * 64 + j];
        g1[nn] = fmaf(v.w, wh.w, fmaf(v.z, wh.z, fmaf(v.y, wh.y, fmaf(v.x, wh.x, g1[nn]))));
      }
    }
    // agg part: W1 at f13 64.., W2 at 320.., W3 at 576..
#pragma unroll
    for (int fa = 0; fa < 4; fa++) {
#pragma unroll
      for (int j = 0; j < 16; j += 4) {
        int o = 64 + fa * 64 + j;
        float4 w1 = *(const float4*)&wbase[o];
        float4 w2 = *(const float4*)&wbase[o + 256];
        float4 w3 = *(const float4*)&wbase[o + 512];
        const float* vfa = &vb[(1 + fa) * 512 + j];
#pragma unroll
        for (int nn = 0; nn < 8; nn++) {
          float4 v = *(const float4*)&vfa[nn * 64];
          g1[nn] = fmaf(v.w, w1.w, fmaf(v.z, w1.z, fmaf(v.y, w1.y, fmaf(v.x, w1.x, g1[nn]))));
          g2[nn] = fmaf(v.w, w2.w, fmaf(v.z, w2.z, fmaf(v.y, w2.y, fmaf(v.x, w2.x, g2[nn]))));
          g3[nn] = fmaf(v.w, w3.w, fmaf(v.z, w3.z, fmaf(v.y, w3.y, fmaf(v.x, w3.x, g3[nn]))));
        }
      }
    }
  }
  // combine with per-node scalars (sAB reads are broadcast)
  float o8[8];
#pragma unroll
  for (int nn = 0; nn < 8; nn++)
    o8[nn] = fmaf(sAB[8 + nn], g3[nn], fmaf(sAB[nn], g2[nn], g1[nn]));
  __syncthreads();   // all sm reads done -> safe to alias

  // ---- partials into aliased region: lpart[node8][tg64][rep4] = sm[0..2047]
  {
    int sw = (w + (lane >> 4)) & 3;
#pragma unroll
    for (int nn = 0; nn < 8; nn++)
      sm[((nn * 64 + lane) << 2) + sw] = o8[nn];
  }
  __syncthreads();

  // ---- reduce + postb -> po at sm[2048 + node*64 + col]
  {
#pragma unroll
    for (int r = 0; r < 2; r++) {
      int idx = r * 256 + (int)threadIdx.x;
      float4 p = *(const float4*)&sm[idx << 2];
      sm[2048 + idx] = p.x + p.y + p.z + p.w + postb[idx & 63];
    }
  }
  __syncthreads();

  // ---- lin epilogue: wave w -> nodes w*2, w*2+1; col = lane
  {
    float acc0 = linb[lane], acc1 = acc0;
    const float* lwt = &linWT[(size_t)lane * 64];
    const float* p0 = &sm[2048 + (w * 2) * 64];
    const float* p1 = p0 + 64;
#pragma unroll
    for (int c = 0; c < 64; c += 4) {
      float4 lw = *(const float4*)&lwt[c];
      float4 pa = *(const float4*)&p0[c];
      float4 pb2 = *(const float4*)&p1[c];
      acc0 = fmaf(pa.w, lw.w, fmaf(pa.z, lw.z, fmaf(pa.y, lw.y, fmaf(pa.x, lw.x, acc0))));
      acc1 = fmaf(pb2.w, lw.w, fmaf(pb2.z, lw.z, fmaf(pb2.y, lw.y, fmaf(pb2.x, lw.x, acc1))));
    }
    size_t ob = (size_t)(n0 + w * 2) * 64 + lane;
    out[ob] = acc0;
    out[ob + 64] = acc1;
  }
}

// ------------------------------------------------------------------ BN stats
__global__ __launch_bounds__(256) void k_bnstats(const float* __restrict__ y,
                                                 float* __restrict__ bnsum,
                                                 float* __restrict__ bnsumsq) {
  __shared__ float r1[256], r2[256];
  int c = threadIdx.x & 63, r = threadIdx.x >> 6;
  float s = 0, q = 0;
  for (int n = blockIdx.x * 4 + r; n < N_NODES; n += gridDim.x * 4) {
    float v = y[(size_t)n * 64 + c];
    s += v; q = fmaf(v, v, q);
  }
  r1[threadIdx.x] = s; r2[threadIdx.x] = q; __syncthreads();
  if (threadIdx.x < 64) {
    s = r1[threadIdx.x] + r1[threadIdx.x + 64] + r1[threadIdx.x + 128] + r1[threadIdx.x + 192];
    q = r2[threadIdx.x] + r2[threadIdx.x + 64] + r2[threadIdx.x + 128] + r2[threadIdx.x + 192];
    atomicAdd(&bnsum[threadIdx.x], s);
    atomicAdd(&bnsumsq[threadIdx.x], q);
  }
}

__global__ void k_bnfin(const float* __restrict__ bnsum, const float* __restrict__ bnsumsq,
                        const float* __restrict__ gamma, const float* __restrict__ beta,
                        float* __restrict__ bnscale, float* __restrict__ bnshift) {
  int c = threadIdx.x;
  if (c < 64) {
    float mu = bnsum[c] * (1.f / N_NODES);
    float var = bnsumsq[c] * (1.f / N_NODES) - mu * mu;
    float sc = gamma[c] / sqrtf(var + BN_EPS);
    bnscale[c] = sc;
    bnshift[c] = fmaf(-mu, sc, beta[c]);
  }
}

// ================================================================== launcher
extern "C" void kernel_launch(void* const* d_in, const int* in_sizes, int n_in,
                              void* d_out, int out_size, void* d_ws, size_t ws_size,
                              hipStream_t stream) {
  const float* x      = (const float*)d_in[0];
  const float* embW   = (const float*)d_in[1];
  const float* embB   = (const float*)d_in[2];
  const float* preW1  = (const float*)d_in[3];
  const float* preb1  = (const float*)d_in[4];
  const float* postW1 = (const float*)d_in[5];
  const float* postb1 = (const float*)d_in[6];
  const float* linW1  = (const float*)d_in[7];
  const float* linb1  = (const float*)d_in[8];
  const float* gamma  = (const float*)d_in[9];
  const float* beta   = (const float*)d_in[10];
  const float* preW2  = (const float*)d_in[11];
  const float* preb2  = (const float*)d_in[12];
  const float* postW2 = (const float*)d_in[13];
  const float* postb2 = (const float*)d_in[14];
  const float* linW2  = (const float*)d_in[15];
  const float* linb2  = (const float*)d_in[16];
  const int*   src    = (const int*)d_in[17];
  const int*   dst    = (const int*)d_in[18];
  float* out = (float*)d_out;

  char* w = (char*)d_ws;
  size_t o = 0;
  int*   deg     = (int*)(w + o);   o += (size_t)N_NODES * 4;
  float* scalars = (float*)(w + o); o += 64;
  float* bnsum   = (float*)(w + o); o += 256;
  float* bnsumsq = (float*)(w + o); o += 256;
  float* bnscale = (float*)(w + o); o += 256;
  float* bnshift = (float*)(w + o); o += 256;
  size_t zero_len = o;
  o = (o + 255) & ~(size_t)255;
  int* partials = (int*)(w + o);  o += 256;
  int* row_ptr  = (int*)(w + o);  o += (size_t)(N_NODES + 1) * 4; o = (o + 255) & ~(size_t)255;
  int* cursor   = (int*)(w + o);  o += (size_t)N_NODES * 4;       o = (o + 255) & ~(size_t)255;
  int* csr      = (int*)(w + o);  o += (size_t)E_EDGES * 4;       o = (o + 255) & ~(size_t)255;
  float* postWT = (float*)(w + o); o += (size_t)2 * 53248 * 4;    // 2 layers
  float* linWT  = (float*)(w + o); o += (size_t)2 * 4096 * 4;
  float* h1 = (float*)(w + o); o += (size_t)N_NODES * 64 * 4;
  float* y1 = (float*)(w + o); o += (size_t)N_NODES * 64 * 4;
  float* h2 = (float*)(w + o); o += (size_t)N_NODES * 64 * 4;
  float* hA = (float*)(w + o); o += (size_t)N_NODES * 128 * 4;
  float* hB = (float*)(w + o); o += (size_t)N_NODES * 128 * 4;

  hipMemsetAsync(w, 0, zero_len, stream);

  const int NBLK_SCAN = (N_NODES + 1023) / 1024;   // 49
  k_hist<<<(E_EDGES + 255) / 256, 256, 0, stream>>>(dst, deg);
  k_sumlog<<<(N_NODES + 255) / 256, 256, 0, stream>>>(deg, scalars);
  k_scan_part<<<NBLK_SCAN, 256, 0, stream>>>(deg, partials);
  k_scan_mid<<<1, 64, 0, stream>>>(partials, NBLK_SCAN, scalars);
  k_scan_final<<<NBLK_SCAN, 256, 0, stream>>>(deg, partials, row_ptr, cursor);
  k_scatter<<<(E_EDGES + 255) / 256, 256, 0, stream>>>(src, dst, cursor, csr);
  k_transpose<<<448, 256, 0, stream>>>(postW1, postW2, linW1, linW2, postWT, linWT);

  k_embed<<<768, 256, 0, stream>>>(x, embW, embB, h1);

  // ----- layer 1
  k_preab<false><<<1024, 256, 0, stream>>>(h1, preW1, preb1, nullptr, nullptr, nullptr, hA, hB);
  k_conv<<<N_NODES / 8, 256, 0, stream>>>(hA, hB, h1, row_ptr, csr,
                                          postWT, postb1, linWT, linb1, scalars, y1);
  // ----- batchnorm
  k_bnstats<<<256, 256, 0, stream>>>(y1, bnsum, bnsumsq);
  k_bnfin<<<1, 64, 0, stream>>>(bnsum, bnsumsq, gamma, beta, bnscale, bnshift);

  // ----- layer 2 (BN+relu fused into staging; h2 materialized for skip)
  k_preab<true><<<1024, 256, 0, stream>>>(y1, preW2, preb2, bnscale, bnshift, h2, hA, hB);
  k_conv<<<N_NODES / 8, 256, 0, stream>>>(hA, hB, h2, row_ptr, csr,
                                          postWT + 53248, postb2, linWT + 4096, linb2,
                                          scalars, out);
}

// Round 5
// 580.809 us; speedup vs baseline: 1.7269x; 1.7269x over previous
//
#include <hip/hip_runtime.h>

#define N_NODES 50000
#define E_EDGES 800000
#define IN_F    128
#define H_F     64
#define STD_EPS 1e-5f
#define BN_EPS  1e-5f

// ---------------------------------------------------------------- degree hist
__global__ __launch_bounds__(256) void k_hist(const int* __restrict__ dst,
                                              int* __restrict__ deg) {
  int e = blockIdx.x * 256 + threadIdx.x;
  if (e < E_EDGES) atomicAdd(&deg[dst[e]], 1);
}

// ------------------------------------------------------- sum of log(deg+1)
__global__ __launch_bounds__(256) void k_sumlog(const int* __restrict__ deg,
                                                float* __restrict__ scalars) {
  __shared__ float red[256];
  int i = blockIdx.x * 256 + threadIdx.x;
  float v = 0.f;
  if (i < N_NODES) v = logf((float)deg[i] + 1.0f);
  red[threadIdx.x] = v; __syncthreads();
  for (int s = 128; s > 0; s >>= 1) {
    if (threadIdx.x < s) red[threadIdx.x] += red[threadIdx.x + s];
    __syncthreads();
  }
  if (threadIdx.x == 0) atomicAdd(&scalars[0], red[0]);
}

// ------------------------------------------------------------- scan (3-phase)
__global__ __launch_bounds__(256) void k_scan_part(const int* __restrict__ deg,
                                                   int* __restrict__ partials) {
  __shared__ int red[256];
  int base = blockIdx.x * 1024;
  int s = 0;
  for (int j = threadIdx.x; j < 1024; j += 256) {
    int i = base + j;
    if (i < N_NODES) s += deg[i];
  }
  red[threadIdx.x] = s; __syncthreads();
  for (int st = 128; st > 0; st >>= 1) {
    if (threadIdx.x < st) red[threadIdx.x] += red[threadIdx.x + st];
    __syncthreads();
  }
  if (threadIdx.x == 0) partials[blockIdx.x] = red[0];
}

__global__ void k_scan_mid(int* __restrict__ partials, int nblk,
                           float* __restrict__ scalars) {
  if (threadIdx.x == 0) {
    int run = 0;
    for (int b = 0; b < nblk; b++) { int v = partials[b]; partials[b] = run; run += v; }
    scalars[1] = scalars[0] / (float)N_NODES;   // avg_log
  }
}

__global__ __launch_bounds__(256) void k_scan_final(const int* __restrict__ deg,
                                                    const int* __restrict__ partials,
                                                    int* __restrict__ row_ptr,
                                                    int* __restrict__ cursor) {
  __shared__ int ts[256];
  int base = blockIdx.x * 1024 + threadIdx.x * 4;
  int d[4]; int s = 0;
#pragma unroll
  for (int j = 0; j < 4; j++) {
    int i = base + j;
    d[j] = (i < N_NODES) ? deg[i] : 0;
    s += d[j];
  }
  ts[threadIdx.x] = s; __syncthreads();
  for (int off = 1; off < 256; off <<= 1) {
    int t = (threadIdx.x >= off) ? ts[threadIdx.x - off] : 0;
    __syncthreads();
    ts[threadIdx.x] += t;
    __syncthreads();
  }
  int excl = (threadIdx.x > 0) ? ts[threadIdx.x - 1] : 0;
  int run = partials[blockIdx.x] + excl;
#pragma unroll
  for (int j = 0; j < 4; j++) {
    int i = base + j;
    if (i < N_NODES) { row_ptr[i] = run; cursor[i] = run; run += d[j]; }
  }
  if (blockIdx.x == 0 && threadIdx.x == 0) row_ptr[N_NODES] = E_EDGES;
}

// ------------------------------------------------------------------- scatter
__global__ __launch_bounds__(256) void k_scatter(const int* __restrict__ src,
                                                 const int* __restrict__ dst,
                                                 int* __restrict__ cursor,
                                                 int* __restrict__ csr_src) {
  int e = blockIdx.x * 256 + threadIdx.x;
  if (e < E_EDGES) {
    int d = dst[e];
    int p = atomicAdd(&cursor[d], 1);
    csr_src[p] = src[e];
  }
}

// --------------------------------------------------------------------- embed
__global__ __launch_bounds__(256) void k_embed(const float* __restrict__ x,
                                               const float* __restrict__ W,
                                               const float* __restrict__ bias,
                                               float* __restrict__ h) {
  __shared__ float sW[IN_F * 64];    // 32 KB
  __shared__ float sx[IN_F * 20];    // x_T[k][16+pad4]
  for (int i = threadIdx.x; i < IN_F * 64; i += 256) sW[i] = W[i];
  int j = threadIdx.x & 63, ng = threadIdx.x >> 6;
  float bj = bias[j];
  for (int grp = blockIdx.x; grp < N_NODES / 16; grp += gridDim.x) {
    int n0 = grp * 16;
    __syncthreads();
    for (int idx = threadIdx.x; idx < 16 * IN_F; idx += 256) {
      int nl = idx >> 7, k = idx & 127;
      sx[k * 20 + nl] = x[(size_t)(n0 + nl) * IN_F + k];
    }
    __syncthreads();
    float a0 = bj, a1 = bj, a2 = bj, a3 = bj;
    const float* xp = &sx[ng * 4];
#pragma unroll 4
    for (int k = 0; k < IN_F; k++) {
      float4 xv = *(const float4*)&xp[k * 20];
      float w = sW[k * 64 + j];
      a0 = fmaf(xv.x, w, a0); a1 = fmaf(xv.y, w, a1);
      a2 = fmaf(xv.z, w, a2); a3 = fmaf(xv.w, w, a3);
    }
    size_t ob = (size_t)(n0 + ng * 4) * 64 + j;
    h[ob] = a0; h[ob + 64] = a1; h[ob + 128] = a2; h[ob + 192] = a3;
  }
}

// ------------------------------------------------------------------ pre A/B
// One TOWER per block (t = blockIdx.x & 1): LDS 32KB -> 4 blocks/CU.
template <bool BN>
__global__ __launch_bounds__(256) void k_preab(const float* __restrict__ hin,
                                               const float* __restrict__ preW,
                                               const float* __restrict__ preb,
                                               const float* __restrict__ bnscale,
                                               const float* __restrict__ bnshift,
                                               float* __restrict__ h2out,
                                               float* __restrict__ hA,
                                               float* __restrict__ hB) {
  __shared__ float sW[128 * 64];   // 32 KB (this tower)
  __shared__ float sh[64 * 20];    // h_T[k][16+pad4]
  int t = blockIdx.x & 1;
  const float* Wsrc = preW + (size_t)t * 128 * 64;
  for (int i = threadIdx.x; i < 128 * 64; i += 256) sW[i] = Wsrc[i];
  int f = threadIdx.x & 63, ng = threadIdx.x >> 6;   // ng in 0..3 -> 4 nodes each
  float pb = preb[t * 64 + f];
  const float* wA = &sW[f];
  const float* wB = &sW[64 * 64 + f];
  int nblk2 = gridDim.x >> 1;
  for (int grp = blockIdx.x >> 1; grp < N_NODES / 16; grp += nblk2) {
    int n0 = grp * 16;
    __syncthreads();
    for (int idx = threadIdx.x; idx < 16 * 64; idx += 256) {
      int nl = idx >> 6, k = idx & 63;
      float v = hin[(size_t)(n0 + nl) * 64 + k];
      if (BN) {
        v = fmaxf(fmaf(v, bnscale[k], bnshift[k]), 0.f);
        if (t == 0) h2out[(size_t)(n0 + nl) * 64 + k] = v;
      }
      sh[k * 20 + nl] = v;
    }
    __syncthreads();
    float a0 = pb, a1 = pb, a2 = pb, a3 = pb;
    float b0 = 0, b1 = 0, b2 = 0, b3 = 0;
    const float* hp = &sh[ng * 4];
#pragma unroll 4
    for (int k = 0; k < 64; k++) {
      float4 hv = *(const float4*)&hp[k * 20];
      float wa = wA[k * 64], wb = wB[k * 64];
      a0 = fmaf(hv.x, wa, a0); a1 = fmaf(hv.y, wa, a1);
      a2 = fmaf(hv.z, wa, a2); a3 = fmaf(hv.w, wa, a3);
      b0 = fmaf(hv.x, wb, b0); b1 = fmaf(hv.y, wb, b1);
      b2 = fmaf(hv.z, wb, b2); b3 = fmaf(hv.w, wb, b3);
    }
    size_t nb = (size_t)(n0 + ng * 4);
    int tf = t * 64 + f;
    hA[nb * 128 + tf] = a0;          hB[nb * 128 + tf] = b0;
    hA[(nb + 1) * 128 + tf] = a1;    hB[(nb + 1) * 128 + tf] = b1;
    hA[(nb + 2) * 128 + tf] = a2;    hB[(nb + 2) * 128 + tf] = b2;
    hA[(nb + 3) * 128 + tf] = a3;    hB[(nb + 3) * 128 + tf] = b3;
  }
}

// --------------------------------------------------- fused conv main kernel
// 8 nodes/block, 4 waves; wave handles 2 nodes' aggregation sequentially.
// LDS stores only the 5 UNIQUE feature slices [t][feat5][node8][hf64] (20KB);
// x1/xSA/xSB expansion factored into G1,G2,G3 per (node,g), combined as
// G1 + sA*G2 + sB*G3.  Weights read from ORIGINAL postW[t][f13*32+g]:
// lane g is stride-1 -> coalesced scalar dword loads (4 lines/wave-load).
__global__ __launch_bounds__(256, 6) void k_conv(const float* __restrict__ hA,
                                                 const float* __restrict__ hB,
                                                 const float* __restrict__ hskip,
                                                 const int* __restrict__ row_ptr,
                                                 const int* __restrict__ csr_src,
                                                 const float* __restrict__ postW,
                                                 const float* __restrict__ postb,
                                                 const float* __restrict__ linW,
                                                 const float* __restrict__ linb,
                                                 const float* __restrict__ scalars,
                                                 float* __restrict__ out) {
  __shared__ float sm[2 * 5 * 8 * 64];   // 20480 B; [(t*5+feat)*512 + node*64 + hf]
  __shared__ float sAB[16];              // sA[0..7], sB[8..15]
  int w = threadIdx.x >> 6, lane = threadIdx.x & 63;
  int n0 = blockIdx.x * 8;
  int t = lane >> 5, fb = (lane & 31) * 2;
  int off = t * 64 + fb;
  float avg = scalars[1];

  // ---- phase A: aggregation, 2 nodes per wave, 4 loads in flight
#pragma unroll 1
  for (int k = 0; k < 2; k++) {
    int nl = w * 2 + k;
    int n = n0 + nl;
    float2 a = *(const float2*)&hA[(size_t)n * 128 + off];
    int rp0 = __builtin_amdgcn_readfirstlane(row_ptr[n]);
    int rp1 = __builtin_amdgcn_readfirstlane(row_ptr[n + 1]);
    float sx0=0,sy0=0,qx0=0,qy0=0, sx1=0,sy1=0,qx1=0,qy1=0;
    float mnx0=INFINITY,mny0=INFINITY,mxx0=-INFINITY,mxy0=-INFINITY;
    float mnx1=INFINITY,mny1=INFINITY,mxx1=-INFINITY,mxy1=-INFINITY;
    int i = rp0;
    int end4 = rp0 + ((rp1 - rp0) & ~3);
    if (i < end4) {
      int s0 = csr_src[i], s1 = csr_src[i+1], s2 = csr_src[i+2], s3 = csr_src[i+3];
      while (true) {
        float2 v0 = *(const float2*)&hB[(size_t)s0 * 128 + off];
        float2 v1 = *(const float2*)&hB[(size_t)s1 * 128 + off];
        float2 v2 = *(const float2*)&hB[(size_t)s2 * 128 + off];
        float2 v3 = *(const float2*)&hB[(size_t)s3 * 128 + off];
        i += 4;
        bool more = (i < end4);
        if (more) { s0 = csr_src[i]; s1 = csr_src[i+1]; s2 = csr_src[i+2]; s3 = csr_src[i+3]; }
        float e0x = v0.x + a.x, e0y = v0.y + a.y;
        float e1x = v1.x + a.x, e1y = v1.y + a.y;
        float e2x = v2.x + a.x, e2y = v2.y + a.y;
        float e3x = v3.x + a.x, e3y = v3.y + a.y;
        sx0 += e0x; qx0 = fmaf(e0x,e0x,qx0); mnx0 = fminf(mnx0,e0x); mxx0 = fmaxf(mxx0,e0x);
        sy0 += e0y; qy0 = fmaf(e0y,e0y,qy0); mny0 = fminf(mny0,e0y); mxy0 = fmaxf(mxy0,e0y);
        sx1 += e1x; qx1 = fmaf(e1x,e1x,qx1); mnx1 = fminf(mnx1,e1x); mxx1 = fmaxf(mxx1,e1x);
        sy1 += e1y; qy1 = fmaf(e1y,e1y,qy1); mny1 = fminf(mny1,e1y); mxy1 = fmaxf(mxy1,e1y);
        sx0 += e2x; qx0 = fmaf(e2x,e2x,qx0); mnx0 = fminf(mnx0,e2x); mxx0 = fmaxf(mxx0,e2x);
        sy0 += e2y; qy0 = fmaf(e2y,e2y,qy0); mny0 = fminf(mny0,e2y); mxy0 = fmaxf(mxy0,e2y);
        sx1 += e3x; qx1 = fmaf(e3x,e3x,qx1); mnx1 = fminf(mnx1,e3x); mxx1 = fmaxf(mxx1,e3x);
        sy1 += e3y; qy1 = fmaf(e3y,e3y,qy1); mny1 = fminf(mny1,e3y); mxy1 = fmaxf(mxy1,e3y);
        if (!more) break;
      }
    }
    {   // masked tail: 0..3 edges, all loads issued together
      int r = rp1 - i;
      if (r > 0) {
        int e1i = (r > 1) ? i + 1 : i;
        int e2i = (r > 2) ? i + 2 : i;
        int t0 = csr_src[i], t1 = csr_src[e1i], t2 = csr_src[e2i];
        float2 u0 = *(const float2*)&hB[(size_t)t0 * 128 + off];
        float2 u1 = *(const float2*)&hB[(size_t)t1 * 128 + off];
        float2 u2 = *(const float2*)&hB[(size_t)t2 * 128 + off];
        float ex = u0.x + a.x, ey = u0.y + a.y;
        sx0 += ex; qx0 = fmaf(ex,ex,qx0); mnx0 = fminf(mnx0,ex); mxx0 = fmaxf(mxx0,ex);
        sy0 += ey; qy0 = fmaf(ey,ey,qy0); mny0 = fminf(mny0,ey); mxy0 = fmaxf(mxy0,ey);
        if (r > 1) {
          ex = u1.x + a.x; ey = u1.y + a.y;
          sx1 += ex; qx1 = fmaf(ex,ex,qx1); mnx1 = fminf(mnx1,ex); mxx1 = fmaxf(mxx1,ex);
          sy1 += ey; qy1 = fmaf(ey,ey,qy1); mny1 = fminf(mny1,ey); mxy1 = fmaxf(mxy1,ey);
        }
        if (r > 2) {
          ex = u2.x + a.x; ey = u2.y + a.y;
          sx0 += ex; qx0 = fmaf(ex,ex,qx0); mnx0 = fminf(mnx0,ex); mxx0 = fmaxf(mxx0,ex);
          sy0 += ey; qy0 = fmaf(ey,ey,qy0); mny0 = fminf(mny0,ey); mxy0 = fmaxf(mxy0,ey);
        }
      }
    }
    int dg = rp1 - rp0;
    float cnt = (float)(dg > 0 ? dg : 1);
    float inv = 1.0f / cnt;
    float meanx = (sx0 + sx1) * inv, meany = (sy0 + sy1) * inv;
    float qx = qx0 + qx1, qy = qy0 + qy1;
    float sdx = sqrtf(fmaxf(qx * inv - meanx * meanx, 0.f) + STD_EPS);
    float sdy = sqrtf(fmaxf(qy * inv - meany * meany, 0.f) + STD_EPS);
    float mnx = fminf(mnx0, mnx1), mny = fminf(mny0, mny1);
    float mxx = fmaxf(mxx0, mxx1), mxy = fmaxf(mxy0, mxy1);
    if (dg == 0) { mnx = 0; mny = 0; mxx = 0; mxy = 0; }
    float ldv = logf(cnt + 1.f);
    float2 hsv = *(const float2*)&hskip[(size_t)n * 64 + fb];
    // write 5 unique slices
    float* bp = &sm[t * 2560 + nl * 64 + fb];
    *(float2*)&bp[0]    = hsv;
    *(float2*)&bp[512]  = make_float2(meanx, meany);
    *(float2*)&bp[1024] = make_float2(mnx, mny);
    *(float2*)&bp[1536] = make_float2(mxx, mxy);
    *(float2*)&bp[2048] = make_float2(sdx, sdy);
    if (lane == 0) { sAB[nl] = ldv / avg; sAB[8 + nl] = avg / ldv; }
  }
  __syncthreads();

  // ---- phase C: factored post matmul; wave w covers hf [w*16, w*16+16)
  float g1[8] = {0,0,0,0,0,0,0,0};
  float g2[8] = {0,0,0,0,0,0,0,0};
  float g3[8] = {0,0,0,0,0,0,0,0};
  {
    int g = lane & 31, hf0 = w * 16;
    const float* pw = &postW[(size_t)t * (832 * 32) + g];   // [f13*32 + g]
    const float* vb = &sm[t * 2560 + hf0];
    // feat0 = h (f13 = hf): G1 only
#pragma unroll
    for (int j = 0; j < 16; j += 4) {
      int f13 = hf0 + j;
      float w0 = pw[f13 * 32],       w1 = pw[(f13 + 1) * 32];
      float w2 = pw[(f13 + 2) * 32], w3 = pw[(f13 + 3) * 32];
#pragma unroll
      for (int nn = 0; nn < 8; nn++) {
        float4 v = *(const float4*)&vb[nn * 64 + j];
        g1[nn] = fmaf(v.w, w3, fmaf(v.z, w2, fmaf(v.y, w1, fmaf(v.x, w0, g1[nn]))));
      }
    }
    // feats 1..4 (agg): G1 at f13=64+fa*64+hf, G2 at +256, G3 at +512
#pragma unroll
    for (int fa = 0; fa < 4; fa++) {
      const float* vfa = &vb[(1 + fa) * 512];
#pragma unroll
      for (int j = 0; j < 16; j += 4) {
        int f13 = 64 + fa * 64 + hf0 + j;
        float w10 = pw[f13 * 32],         w11 = pw[(f13 + 1) * 32];
        float w12 = pw[(f13 + 2) * 32],   w13 = pw[(f13 + 3) * 32];
        float w20 = pw[(f13 + 256) * 32], w21 = pw[(f13 + 257) * 32];
        float w22 = pw[(f13 + 258) * 32], w23 = pw[(f13 + 259) * 32];
        float w30 = pw[(f13 + 512) * 32], w31 = pw[(f13 + 513) * 32];
        float w32 = pw[(f13 + 514) * 32], w33 = pw[(f13 + 515) * 32];
#pragma unroll
        for (int nn = 0; nn < 8; nn++) {
          float4 v = *(const float4*)&vfa[nn * 64 + j];
          g1[nn] = fmaf(v.w, w13, fmaf(v.z, w12, fmaf(v.y, w11, fmaf(v.x, w10, g1[nn]))));
          g2[nn] = fmaf(v.w, w23, fmaf(v.z, w22, fmaf(v.y, w21, fmaf(v.x, w20, g2[nn]))));
          g3[nn] = fmaf(v.w, w33, fmaf(v.z, w32, fmaf(v.y, w31, fmaf(v.x, w30, g3[nn]))));
        }
      }
    }
  }
  // combine with per-node scalars (sAB reads are broadcast)
  float o8[8];
#pragma unroll
  for (int nn = 0; nn < 8; nn++)
    o8[nn] = fmaf(sAB[8 + nn], g3[nn], fmaf(sAB[nn], g2[nn], g1[nn]));
  __syncthreads();   // all sm reads done -> safe to alias

  // ---- partials into aliased region: lpart[node8][tg64][rep4] = sm[0..2047]
  {
    int sw = (w + (lane >> 4)) & 3;
#pragma unroll
    for (int nn = 0; nn < 8; nn++)
      sm[((nn * 64 + lane) << 2) + sw] = o8[nn];
  }
  __syncthreads();

  // ---- reduce + postb -> po at sm[2048 + node*64 + col]
  {
#pragma unroll
    for (int r = 0; r < 2; r++) {
      int idx = r * 256 + (int)threadIdx.x;
      float4 p = *(const float4*)&sm[idx << 2];
      sm[2048 + idx] = p.x + p.y + p.z + p.w + postb[idx & 63];
    }
  }
  __syncthreads();

  // ---- lin epilogue: wave w -> nodes w*2, w*2+1; col = lane
  // original linW [row][col]: lane=col -> coalesced scalar loads, shared by
  // both nodes' FMAs.
  {
    float acc0 = linb[lane], acc1 = acc0;
    const float* lw = linW + lane;
    const float* p0 = &sm[2048 + (w * 2) * 64];
    const float* p1 = p0 + 64;
#pragma unroll
    for (int c = 0; c < 64; c += 4) {
      float lw0 = lw[c * 64], lw1 = lw[(c + 1) * 64];
      float lw2 = lw[(c + 2) * 64], lw3 = lw[(c + 3) * 64];
      float4 pa = *(const float4*)&p0[c];
      float4 pb2 = *(const float4*)&p1[c];
      acc0 = fmaf(pa.w, lw3, fmaf(pa.z, lw2, fmaf(pa.y, lw1, fmaf(pa.x, lw0, acc0))));
      acc1 = fmaf(pb2.w, lw3, fmaf(pb2.z, lw2, fmaf(pb2.y, lw1, fmaf(pb2.x, lw0, acc1))));
    }
    size_t ob = (size_t)(n0 + w * 2) * 64 + lane;
    out[ob] = acc0;
    out[ob + 64] = acc1;
  }
}

// ------------------------------------------------------------------ BN stats
__global__ __launch_bounds__(256) void k_bnstats(const float* __restrict__ y,
                                                 float* __restrict__ bnsum,
                                                 float* __restrict__ bnsumsq) {
  __shared__ float r1[256], r2[256];
  int c = threadIdx.x & 63, r = threadIdx.x >> 6;
  float s = 0, q = 0;
  for (int n = blockIdx.x * 4 + r; n < N_NODES; n += gridDim.x * 4) {
    float v = y[(size_t)n * 64 + c];
    s += v; q = fmaf(v, v, q);
  }
  r1[threadIdx.x] = s; r2[threadIdx.x] = q; __syncthreads();
  if (threadIdx.x < 64) {
    s = r1[threadIdx.x] + r1[threadIdx.x + 64] + r1[threadIdx.x + 128] + r1[threadIdx.x + 192];
    q = r2[threadIdx.x] + r2[threadIdx.x + 64] + r2[threadIdx.x + 128] + r2[threadIdx.x + 192];
    atomicAdd(&bnsum[threadIdx.x], s);
    atomicAdd(&bnsumsq[threadIdx.x], q);
  }
}

__global__ void k_bnfin(const float* __restrict__ bnsum, const float* __restrict__ bnsumsq,
                        const float* __restrict__ gamma, const float* __restrict__ beta,
                        float* __restrict__ bnscale, float* __restrict__ bnshift) {
  int c = threadIdx.x;
  if (c < 64) {
    float mu = bnsum[c] * (1.f / N_NODES);
    float var = bnsumsq[c] * (1.f / N_NODES) - mu * mu;
    float sc = gamma[c] / sqrtf(var + BN_EPS);
    bnscale[c] = sc;
    bnshift[c] = fmaf(-mu, sc, beta[c]);
  }
}

// ================================================================== launcher
extern "C" void kernel_launch(void* const* d_in, const int* in_sizes, int n_in,
                              void* d_out, int out_size, void* d_ws, size_t ws_size,
                              hipStream_t stream) {
  const float* x      = (const float*)d_in[0];
  const float* embW   = (const float*)d_in[1];
  const float* embB   = (const float*)d_in[2];
  const float* preW1  = (const float*)d_in[3];
  const float* preb1  = (const float*)d_in[4];
  const float* postW1 = (const float*)d_in[5];
  const float* postb1 = (const float*)d_in[6];
  const float* linW1  = (const float*)d_in[7];
  const float* linb1  = (const float*)d_in[8];
  const float* gamma  = (const float*)d_in[9];
  const float* beta   = (const float*)d_in[10];
  const float* preW2  = (const float*)d_in[11];
  const float* preb2  = (const float*)d_in[12];
  const float* postW2 = (const float*)d_in[13];
  const float* postb2 = (const float*)d_in[14];
  const float* linW2  = (const float*)d_in[15];
  const float* linb2  = (const float*)d_in[16];
  const int*   src    = (const int*)d_in[17];
  const int*   dst    = (const int*)d_in[18];
  float* out = (float*)d_out;

  char* w = (char*)d_ws;
  size_t o = 0;
  int*   deg     = (int*)(w + o);   o += (size_t)N_NODES * 4;
  float* scalars = (float*)(w + o); o += 64;
  float* bnsum   = (float*)(w + o); o += 256;
  float* bnsumsq = (float*)(w + o); o += 256;
  float* bnscale = (float*)(w + o); o += 256;
  float* bnshift = (float*)(w + o); o += 256;
  size_t zero_len = o;
  o = (o + 255) & ~(size_t)255;
  int* partials = (int*)(w + o);  o += 256;
  int* row_ptr  = (int*)(w + o);  o += (size_t)(N_NODES + 1) * 4; o = (o + 255) & ~(size_t)255;
  int* cursor   = (int*)(w + o);  o += (size_t)N_NODES * 4;       o = (o + 255) & ~(size_t)255;
  int* csr      = (int*)(w + o);  o += (size_t)E_EDGES * 4;       o = (o + 255) & ~(size_t)255;
  float* h1 = (float*)(w + o); o += (size_t)N_NODES * 64 * 4;
  float* y1 = (float*)(w + o); o += (size_t)N_NODES * 64 * 4;
  float* h2 = (float*)(w + o); o += (size_t)N_NODES * 64 * 4;
  float* hA = (float*)(w + o); o += (size_t)N_NODES * 128 * 4;
  float* hB = (float*)(w + o); o += (size_t)N_NODES * 128 * 4;

  hipMemsetAsync(w, 0, zero_len, stream);

  const int NBLK_SCAN = (N_NODES + 1023) / 1024;   // 49
  k_hist<<<(E_EDGES + 255) / 256, 256, 0, stream>>>(dst, deg);
  k_sumlog<<<(N_NODES + 255) / 256, 256, 0, stream>>>(deg, scalars);
  k_scan_part<<<NBLK_SCAN, 256, 0, stream>>>(deg, partials);
  k_scan_mid<<<1, 64, 0, stream>>>(partials, NBLK_SCAN, scalars);
  k_scan_final<<<NBLK_SCAN, 256, 0, stream>>>(deg, partials, row_ptr, cursor);
  k_scatter<<<(E_EDGES + 255) / 256, 256, 0, stream>>>(src, dst, cursor, csr);

  k_embed<<<768, 256, 0, stream>>>(x, embW, embB, h1);

  // ----- layer 1
  k_preab<false><<<1024, 256, 0, stream>>>(h1, preW1, preb1, nullptr, nullptr, nullptr, hA, hB);
  k_conv<<<N_NODES / 8, 256, 0, stream>>>(hA, hB, h1, row_ptr, csr,
                                          postW1, postb1, linW1, linb1, scalars, y1);
  // ----- batchnorm
  k_bnstats<<<256, 256, 0, stream>>>(y1, bnsum, bnsumsq);
  k_bnfin<<<1, 64, 0, stream>>>(bnsum, bnsumsq, gamma, beta, bnscale, bnshift);

  // ----- layer 2 (BN+relu fused into staging; h2 materialized for skip)
  k_preab<true><<<1024, 256, 0, stream>>>(y1, preW2, preb2, bnscale, bnshift, h2, hA, hB);
  k_conv<<<N_NODES / 8, 256, 0, stream>>>(hA, hB, h2, row_ptr, csr,
                                          postW2, postb2, linW2, linb2, scalars, out);
}

// Round 6
// 574.356 us; speedup vs baseline: 1.7463x; 1.0112x over previous
//
#include <hip/hip_runtime.h>

#define N_NODES 50000
#define E_EDGES 800000
#define IN_F    128
#define H_F     64
#define STD_EPS 1e-5f
#define BN_EPS  1e-5f

// ---------------------------------------------------------------- degree hist
__global__ __launch_bounds__(256) void k_hist(const int* __restrict__ dst,
                                              int* __restrict__ deg) {
  int e = blockIdx.x * 256 + threadIdx.x;
  if (e < E_EDGES) atomicAdd(&deg[dst[e]], 1);
}

// ------------------------------------------------------- sum of log(deg+1)
__global__ __launch_bounds__(256) void k_sumlog(const int* __restrict__ deg,
                                                float* __restrict__ scalars) {
  __shared__ float red[256];
  int i = blockIdx.x * 256 + threadIdx.x;
  float v = 0.f;
  if (i < N_NODES) v = logf((float)deg[i] + 1.0f);
  red[threadIdx.x] = v; __syncthreads();
  for (int s = 128; s > 0; s >>= 1) {
    if (threadIdx.x < s) red[threadIdx.x] += red[threadIdx.x + s];
    __syncthreads();
  }
  if (threadIdx.x == 0) atomicAdd(&scalars[0], red[0]);
}

// ------------------------------------------------------------- scan (3-phase)
__global__ __launch_bounds__(256) void k_scan_part(const int* __restrict__ deg,
                                                   int* __restrict__ partials) {
  __shared__ int red[256];
  int base = blockIdx.x * 1024;
  int s = 0;
  for (int j = threadIdx.x; j < 1024; j += 256) {
    int i = base + j;
    if (i < N_NODES) s += deg[i];
  }
  red[threadIdx.x] = s; __syncthreads();
  for (int st = 128; st > 0; st >>= 1) {
    if (threadIdx.x < st) red[threadIdx.x] += red[threadIdx.x + st];
    __syncthreads();
  }
  if (threadIdx.x == 0) partials[blockIdx.x] = red[0];
}

__global__ void k_scan_mid(int* __restrict__ partials, int nblk,
                           float* __restrict__ scalars) {
  if (threadIdx.x == 0) {
    int run = 0;
    for (int b = 0; b < nblk; b++) { int v = partials[b]; partials[b] = run; run += v; }
    scalars[1] = scalars[0] / (float)N_NODES;   // avg_log
  }
}

__global__ __launch_bounds__(256) void k_scan_final(const int* __restrict__ deg,
                                                    const int* __restrict__ partials,
                                                    int* __restrict__ row_ptr,
                                                    int* __restrict__ cursor) {
  __shared__ int ts[256];
  int base = blockIdx.x * 1024 + threadIdx.x * 4;
  int d[4]; int s = 0;
#pragma unroll
  for (int j = 0; j < 4; j++) {
    int i = base + j;
    d[j] = (i < N_NODES) ? deg[i] : 0;
    s += d[j];
  }
  ts[threadIdx.x] = s; __syncthreads();
  for (int off = 1; off < 256; off <<= 1) {
    int t = (threadIdx.x >= off) ? ts[threadIdx.x - off] : 0;
    __syncthreads();
    ts[threadIdx.x] += t;
    __syncthreads();
  }
  int excl = (threadIdx.x > 0) ? ts[threadIdx.x - 1] : 0;
  int run = partials[blockIdx.x] + excl;
#pragma unroll
  for (int j = 0; j < 4; j++) {
    int i = base + j;
    if (i < N_NODES) { row_ptr[i] = run; cursor[i] = run; run += d[j]; }
  }
  if (blockIdx.x == 0 && threadIdx.x == 0) row_ptr[N_NODES] = E_EDGES;
}

// ------------------------------------------------------------------- scatter
__global__ __launch_bounds__(256) void k_scatter(const int* __restrict__ src,
                                                 const int* __restrict__ dst,
                                                 int* __restrict__ cursor,
                                                 int* __restrict__ csr_src) {
  int e = blockIdx.x * 256 + threadIdx.x;
  if (e < E_EDGES) {
    int d = dst[e];
    int p = atomicAdd(&cursor[d], 1);
    csr_src[p] = src[e];
  }
}

// --------------------------------------------------------------------- embed
__global__ __launch_bounds__(256) void k_embed(const float* __restrict__ x,
                                               const float* __restrict__ W,
                                               const float* __restrict__ bias,
                                               float* __restrict__ h) {
  __shared__ float sW[IN_F * 64];    // 32 KB
  __shared__ float sx[IN_F * 20];    // x_T[k][16+pad4]
  for (int i = threadIdx.x; i < IN_F * 64; i += 256) sW[i] = W[i];
  int j = threadIdx.x & 63, ng = threadIdx.x >> 6;
  float bj = bias[j];
  for (int grp = blockIdx.x; grp < N_NODES / 16; grp += gridDim.x) {
    int n0 = grp * 16;
    __syncthreads();
    for (int idx = threadIdx.x; idx < 16 * IN_F; idx += 256) {
      int nl = idx >> 7, k = idx & 127;
      sx[k * 20 + nl] = x[(size_t)(n0 + nl) * IN_F + k];
    }
    __syncthreads();
    float a0 = bj, a1 = bj, a2 = bj, a3 = bj;
    const float* xp = &sx[ng * 4];
#pragma unroll 4
    for (int k = 0; k < IN_F; k++) {
      float4 xv = *(const float4*)&xp[k * 20];
      float w = sW[k * 64 + j];
      a0 = fmaf(xv.x, w, a0); a1 = fmaf(xv.y, w, a1);
      a2 = fmaf(xv.z, w, a2); a3 = fmaf(xv.w, w, a3);
    }
    size_t ob = (size_t)(n0 + ng * 4) * 64 + j;
    h[ob] = a0; h[ob + 64] = a1; h[ob + 128] = a2; h[ob + 192] = a3;
  }
}

// ------------------------------------------------------------------ pre A/B
// One TOWER per block (t = blockIdx.x & 1).  32-node groups, 8 nodes/thread.
// Weights packed interleaved: sWp[k*128 + f*2 + {0,1}] = {Wa[k,f], Wb[k,f]}
//   -> k-loop reads ONE b64 weight + TWO broadcast b128 h-reads per 16 FMA.
template <bool BN>
__global__ __launch_bounds__(256) void k_preab(const float* __restrict__ hin,
                                               const float* __restrict__ preW,
                                               const float* __restrict__ preb,
                                               const float* __restrict__ bnscale,
                                               const float* __restrict__ bnshift,
                                               float* __restrict__ h2out,
                                               float* __restrict__ hA,
                                               float* __restrict__ hB) {
  __shared__ float sWp[64 * 128];   // 32 KB packed [k][f][{A,B}]
  __shared__ float sh[64 * 36];     // h_T[k][32+pad4]  9216 B
  int t = blockIdx.x & 1;
  const float* Wsrc = preW + (size_t)t * 128 * 64;
  for (int i = threadIdx.x; i < 64 * 64; i += 256) {
    int k = i >> 6, f = i & 63;
    float wa = Wsrc[k * 64 + f];
    float wb = Wsrc[(64 + k) * 64 + f];
    *(float2*)&sWp[k * 128 + f * 2] = make_float2(wa, wb);
  }
  int f = threadIdx.x & 63, ng = threadIdx.x >> 6;   // ng 0..3 -> 8 nodes each
  float pb = preb[t * 64 + f];
  int nblk2 = gridDim.x >> 1;
  const int NGRP = (N_NODES + 31) / 32;   // 1563
  for (int grp = blockIdx.x >> 1; grp < NGRP; grp += nblk2) {
    int n0 = grp * 32;
    __syncthreads();
    for (int idx = threadIdx.x; idx < 32 * 64; idx += 256) {
      int nl = idx >> 6, k = idx & 63;
      int n = n0 + nl;
      float v = 0.f;
      if (n < N_NODES) {
        v = hin[(size_t)n * 64 + k];
        if (BN) {
          v = fmaxf(fmaf(v, bnscale[k], bnshift[k]), 0.f);
          if (t == 0) h2out[(size_t)n * 64 + k] = v;
        }
      }
      sh[k * 36 + nl] = v;
    }
    __syncthreads();
    float a[8] = {pb, pb, pb, pb, pb, pb, pb, pb};
    float b[8] = {0, 0, 0, 0, 0, 0, 0, 0};
    const float* hp = &sh[ng * 8];
    const float* wp = &sWp[f * 2];
#pragma unroll 4
    for (int k = 0; k < 64; k++) {
      float4 h0 = *(const float4*)&hp[k * 36];
      float4 h1 = *(const float4*)&hp[k * 36 + 4];
      float2 w2 = *(const float2*)&wp[k * 128];
      a[0] = fmaf(h0.x, w2.x, a[0]); b[0] = fmaf(h0.x, w2.y, b[0]);
      a[1] = fmaf(h0.y, w2.x, a[1]); b[1] = fmaf(h0.y, w2.y, b[1]);
      a[2] = fmaf(h0.z, w2.x, a[2]); b[2] = fmaf(h0.z, w2.y, b[2]);
      a[3] = fmaf(h0.w, w2.x, a[3]); b[3] = fmaf(h0.w, w2.y, b[3]);
      a[4] = fmaf(h1.x, w2.x, a[4]); b[4] = fmaf(h1.x, w2.y, b[4]);
      a[5] = fmaf(h1.y, w2.x, a[5]); b[5] = fmaf(h1.y, w2.y, b[5]);
      a[6] = fmaf(h1.z, w2.x, a[6]); b[6] = fmaf(h1.z, w2.y, b[6]);
      a[7] = fmaf(h1.w, w2.x, a[7]); b[7] = fmaf(h1.w, w2.y, b[7]);
    }
    int tf = t * 64 + f;
#pragma unroll
    for (int j = 0; j < 8; j++) {
      int n = n0 + ng * 8 + j;
      if (n < N_NODES) {
        hA[(size_t)n * 128 + tf] = a[j];
        hB[(size_t)n * 128 + tf] = b[j];
      }
    }
  }
}

// --------------------------------------------------- fused conv main kernel
// 16 nodes/block, 4 waves; wave aggregates 4 nodes sequentially.
// LDS = 5 unique slices [t][feat5][node16][hf64] = 40960 B exactly
//   -> 4 blocks/CU.  sA/sB recomputed from row_ptr in the combine step.
// Factored accumulators G1,G2,G3; combined as G1 + sA*G2 + sB*G3.
// postW read in ORIGINAL [f13*32+g] layout (lane-coalesced); 208 weight
// loads/thread now serve 16 nodes.
__global__ __launch_bounds__(256, 4) void k_conv(const float* __restrict__ hA,
                                                 const float* __restrict__ hB,
                                                 const float* __restrict__ hskip,
                                                 const int* __restrict__ row_ptr,
                                                 const int* __restrict__ csr_src,
                                                 const float* __restrict__ postW,
                                                 const float* __restrict__ postb,
                                                 const float* __restrict__ linW,
                                                 const float* __restrict__ linb,
                                                 const float* __restrict__ scalars,
                                                 float* __restrict__ out) {
  __shared__ float sm[2 * 5 * 16 * 64];   // 40960 B
  int w = threadIdx.x >> 6, lane = threadIdx.x & 63;
  int n0 = blockIdx.x * 16;               // N divisible by 16
  int t = lane >> 5, fb = (lane & 31) * 2;
  int off = t * 64 + fb;
  float avg = scalars[1];

  // ---- phase A: aggregation, 4 nodes per wave, 4 loads in flight
#pragma unroll 1
  for (int kk = 0; kk < 4; kk++) {
    int nl = w * 4 + kk;
    int n = n0 + nl;
    float2 a = *(const float2*)&hA[(size_t)n * 128 + off];
    int rp0 = __builtin_amdgcn_readfirstlane(row_ptr[n]);
    int rp1 = __builtin_amdgcn_readfirstlane(row_ptr[n + 1]);
    float sx0=0,sy0=0,qx0=0,qy0=0, sx1=0,sy1=0,qx1=0,qy1=0;
    float mnx0=INFINITY,mny0=INFINITY,mxx0=-INFINITY,mxy0=-INFINITY;
    float mnx1=INFINITY,mny1=INFINITY,mxx1=-INFINITY,mxy1=-INFINITY;
    int i = rp0;
    int end4 = rp0 + ((rp1 - rp0) & ~3);
    if (i < end4) {
      int s0 = csr_src[i], s1 = csr_src[i+1], s2 = csr_src[i+2], s3 = csr_src[i+3];
      while (true) {
        float2 v0 = *(const float2*)&hB[(size_t)s0 * 128 + off];
        float2 v1 = *(const float2*)&hB[(size_t)s1 * 128 + off];
        float2 v2 = *(const float2*)&hB[(size_t)s2 * 128 + off];
        float2 v3 = *(const float2*)&hB[(size_t)s3 * 128 + off];
        i += 4;
        bool more = (i < end4);
        if (more) { s0 = csr_src[i]; s1 = csr_src[i+1]; s2 = csr_src[i+2]; s3 = csr_src[i+3]; }
        float e0x = v0.x + a.x, e0y = v0.y + a.y;
        float e1x = v1.x + a.x, e1y = v1.y + a.y;
        float e2x = v2.x + a.x, e2y = v2.y + a.y;
        float e3x = v3.x + a.x, e3y = v3.y + a.y;
        sx0 += e0x; qx0 = fmaf(e0x,e0x,qx0); mnx0 = fminf(mnx0,e0x); mxx0 = fmaxf(mxx0,e0x);
        sy0 += e0y; qy0 = fmaf(e0y,e0y,qy0); mny0 = fminf(mny0,e0y); mxy0 = fmaxf(mxy0,e0y);
        sx1 += e1x; qx1 = fmaf(e1x,e1x,qx1); mnx1 = fminf(mnx1,e1x); mxx1 = fmaxf(mxx1,e1x);
        sy1 += e1y; qy1 = fmaf(e1y,e1y,qy1); mny1 = fminf(mny1,e1y); mxy1 = fmaxf(mxy1,e1y);
        sx0 += e2x; qx0 = fmaf(e2x,e2x,qx0); mnx0 = fminf(mnx0,e2x); mxx0 = fmaxf(mxx0,e2x);
        sy0 += e2y; qy0 = fmaf(e2y,e2y,qy0); mny0 = fminf(mny0,e2y); mxy0 = fmaxf(mxy0,e2y);
        sx1 += e3x; qx1 = fmaf(e3x,e3x,qx1); mnx1 = fminf(mnx1,e3x); mxx1 = fmaxf(mxx1,e3x);
        sy1 += e3y; qy1 = fmaf(e3y,e3y,qy1); mny1 = fminf(mny1,e3y); mxy1 = fmaxf(mxy1,e3y);
        if (!more) break;
      }
    }
    {   // masked tail: 0..3 edges, all loads issued together
      int r = rp1 - i;
      if (r > 0) {
        int e1i = (r > 1) ? i + 1 : i;
        int e2i = (r > 2) ? i + 2 : i;
        int t0 = csr_src[i], t1 = csr_src[e1i], t2 = csr_src[e2i];
        float2 u0 = *(const float2*)&hB[(size_t)t0 * 128 + off];
        float2 u1 = *(const float2*)&hB[(size_t)t1 * 128 + off];
        float2 u2 = *(const float2*)&hB[(size_t)t2 * 128 + off];
        float ex = u0.x + a.x, ey = u0.y + a.y;
        sx0 += ex; qx0 = fmaf(ex,ex,qx0); mnx0 = fminf(mnx0,ex); mxx0 = fmaxf(mxx0,ex);
        sy0 += ey; qy0 = fmaf(ey,ey,qy0); mny0 = fminf(mny0,ey); mxy0 = fmaxf(mxy0,ey);
        if (r > 1) {
          ex = u1.x + a.x; ey = u1.y + a.y;
          sx1 += ex; qx1 = fmaf(ex,ex,qx1); mnx1 = fminf(mnx1,ex); mxx1 = fmaxf(mxx1,ex);
          sy1 += ey; qy1 = fmaf(ey,ey,qy1); mny1 = fminf(mny1,ey); mxy1 = fmaxf(mxy1,ey);
        }
        if (r > 2) {
          ex = u2.x + a.x; ey = u2.y + a.y;
          sx0 += ex; qx0 = fmaf(ex,ex,qx0); mnx0 = fminf(mnx0,ex); mxx0 = fmaxf(mxx0,ex);
          sy0 += ey; qy0 = fmaf(ey,ey,qy0); mny0 = fminf(mny0,ey); mxy0 = fmaxf(mxy0,ey);
        }
      }
    }
    int dg = rp1 - rp0;
    float cnt = (float)(dg > 0 ? dg : 1);
    float inv = 1.0f / cnt;
    float meanx = (sx0 + sx1) * inv, meany = (sy0 + sy1) * inv;
    float qx = qx0 + qx1, qy = qy0 + qy1;
    float sdx = sqrtf(fmaxf(qx * inv - meanx * meanx, 0.f) + STD_EPS);
    float sdy = sqrtf(fmaxf(qy * inv - meany * meany, 0.f) + STD_EPS);
    float mnx = fminf(mnx0, mnx1), mny = fminf(mny0, mny1);
    float mxx = fmaxf(mxx0, mxx1), mxy = fmaxf(mxy0, mxy1);
    if (dg == 0) { mnx = 0; mny = 0; mxx = 0; mxy = 0; }
    float2 hsv = *(const float2*)&hskip[(size_t)n * 64 + fb];
    // write 5 unique slices: [t*5120 + feat*1024 + nl*64 + hf]
    float* bp = &sm[t * 5120 + nl * 64 + fb];
    *(float2*)&bp[0]    = hsv;
    *(float2*)&bp[1024] = make_float2(meanx, meany);
    *(float2*)&bp[2048] = make_float2(mnx, mny);
    *(float2*)&bp[3072] = make_float2(mxx, mxy);
    *(float2*)&bp[4096] = make_float2(sdx, sdy);
  }
  __syncthreads();

  // ---- phase C: factored post matmul; wave w covers hf [w*16, w*16+16)
  float g1[16], g2[16], g3[16];
#pragma unroll
  for (int nn = 0; nn < 16; nn++) { g1[nn] = 0; g2[nn] = 0; g3[nn] = 0; }
  {
    int g = lane & 31, hf0 = w * 16;
    const float* pw = &postW[(size_t)t * (832 * 32) + g];   // [f13*32 + g]
    const float* vb = &sm[t * 5120 + hf0];
    // feat0 = h: G1 only
#pragma unroll
    for (int j = 0; j < 16; j += 4) {
      int f13 = hf0 + j;
      float w0 = pw[f13 * 32],       w1 = pw[(f13 + 1) * 32];
      float w2 = pw[(f13 + 2) * 32], w3 = pw[(f13 + 3) * 32];
#pragma unroll
      for (int nn = 0; nn < 16; nn++) {
        float4 v = *(const float4*)&vb[nn * 64 + j];
        g1[nn] = fmaf(v.w, w3, fmaf(v.z, w2, fmaf(v.y, w1, fmaf(v.x, w0, g1[nn]))));
      }
    }
    // feats 1..4 (agg): G1 at f13=64+fa*64+hf, G2 at +256, G3 at +512
#pragma unroll
    for (int fa = 0; fa < 4; fa++) {
      const float* vfa = &vb[(1 + fa) * 1024];
#pragma unroll
      for (int j = 0; j < 16; j += 4) {
        int f13 = 64 + fa * 64 + hf0 + j;
        float w10 = pw[f13 * 32],         w11 = pw[(f13 + 1) * 32];
        float w12 = pw[(f13 + 2) * 32],   w13 = pw[(f13 + 3) * 32];
        float w20 = pw[(f13 + 256) * 32], w21 = pw[(f13 + 257) * 32];
        float w22 = pw[(f13 + 258) * 32], w23 = pw[(f13 + 259) * 32];
        float w30 = pw[(f13 + 512) * 32], w31 = pw[(f13 + 513) * 32];
        float w32 = pw[(f13 + 514) * 32], w33 = pw[(f13 + 515) * 32];
#pragma unroll
        for (int nn = 0; nn < 16; nn++) {
          float4 v = *(const float4*)&vfa[nn * 64 + j];
          g1[nn] = fmaf(v.w, w13, fmaf(v.z, w12, fmaf(v.y, w11, fmaf(v.x, w10, g1[nn]))));
          g2[nn] = fmaf(v.w, w23, fmaf(v.z, w22, fmaf(v.y, w21, fmaf(v.x, w20, g2[nn]))));
          g3[nn] = fmaf(v.w, w33, fmaf(v.z, w32, fmaf(v.y, w31, fmaf(v.x, w30, g3[nn]))));
        }
      }
    }
  }
  // combine with per-node scalars, recomputed from row_ptr (scalar loads)
  float o16[16];
#pragma unroll
  for (int nn = 0; nn < 16; nn++) {
    int dgn = row_ptr[n0 + nn + 1] - row_ptr[n0 + nn];
    float cntn = (float)(dgn > 0 ? dgn : 1);
    float ldv = logf(cntn + 1.f);
    float sA = ldv / avg, sB = avg / ldv;
    o16[nn] = fmaf(sB, g3[nn], fmaf(sA, g2[nn], g1[nn]));
  }
  __syncthreads();   // all sm reads done -> safe to alias

  // ---- partials into aliased region: sm[0..4095] = [node16][tg64][rep4]
  {
    int sw = (w + (lane >> 4)) & 3;
#pragma unroll
    for (int nn = 0; nn < 16; nn++)
      sm[((nn * 64 + lane) << 2) + sw] = o16[nn];
  }
  __syncthreads();

  // ---- reduce + postb -> po at sm[4096 + node*64 + col]
  {
#pragma unroll
    for (int r = 0; r < 4; r++) {
      int idx = r * 256 + (int)threadIdx.x;
      float4 p = *(const float4*)&sm[idx << 2];
      sm[4096 + idx] = p.x + p.y + p.z + p.w + postb[idx & 63];
    }
  }
  __syncthreads();

  // ---- lin epilogue: wave w -> nodes w*4 .. w*4+3; col = lane
  {
    float lb = linb[lane];
    float acc0 = lb, acc1 = lb, acc2 = lb, acc3 = lb;
    const float* lw = linW + lane;
    const float* p0 = &sm[4096 + (w * 4) * 64];
#pragma unroll
    for (int c = 0; c < 64; c += 4) {
      float lw0 = lw[c * 64], lw1 = lw[(c + 1) * 64];
      float lw2 = lw[(c + 2) * 64], lw3 = lw[(c + 3) * 64];
      float4 pa = *(const float4*)&p0[c];
      float4 pb = *(const float4*)&p0[64 + c];
      float4 pc = *(const float4*)&p0[128 + c];
      float4 pd = *(const float4*)&p0[192 + c];
      acc0 = fmaf(pa.w, lw3, fmaf(pa.z, lw2, fmaf(pa.y, lw1, fmaf(pa.x, lw0, acc0))));
      acc1 = fmaf(pb.w, lw3, fmaf(pb.z, lw2, fmaf(pb.y, lw1, fmaf(pb.x, lw0, acc1))));
      acc2 = fmaf(pc.w, lw3, fmaf(pc.z, lw2, fmaf(pc.y, lw1, fmaf(pc.x, lw0, acc2))));
      acc3 = fmaf(pd.w, lw3, fmaf(pd.z, lw2, fmaf(pd.y, lw1, fmaf(pd.x, lw0, acc3))));
    }
    size_t ob = (size_t)(n0 + w * 4) * 64 + lane;
    out[ob] = acc0; out[ob + 64] = acc1; out[ob + 128] = acc2; out[ob + 192] = acc3;
  }
}

// ------------------------------------------------------------------ BN stats
__global__ __launch_bounds__(256) void k_bnstats(const float* __restrict__ y,
                                                 float* __restrict__ bnsum,
                                                 float* __restrict__ bnsumsq) {
  __shared__ float r1[256], r2[256];
  int c = threadIdx.x & 63, r = threadIdx.x >> 6;
  float s = 0, q = 0;
  for (int n = blockIdx.x * 4 + r; n < N_NODES; n += gridDim.x * 4) {
    float v = y[(size_t)n * 64 + c];
    s += v; q = fmaf(v, v, q);
  }
  r1[threadIdx.x] = s; r2[threadIdx.x] = q; __syncthreads();
  if (threadIdx.x < 64) {
    s = r1[threadIdx.x] + r1[threadIdx.x + 64] + r1[threadIdx.x + 128] + r1[threadIdx.x + 192];
    q = r2[threadIdx.x] + r2[threadIdx.x + 64] + r2[threadIdx.x + 128] + r2[threadIdx.x + 192];
    atomicAdd(&bnsum[threadIdx.x], s);
    atomicAdd(&bnsumsq[threadIdx.x], q);
  }
}

__global__ void k_bnfin(const float* __restrict__ bnsum, const float* __restrict__ bnsumsq,
                        const float* __restrict__ gamma, const float* __restrict__ beta,
                        float* __restrict__ bnscale, float* __restrict__ bnshift) {
  int c = threadIdx.x;
  if (c < 64) {
    float mu = bnsum[c] * (1.f / N_NODES);
    float var = bnsumsq[c] * (1.f / N_NODES) - mu * mu;
    float sc = gamma[c] / sqrtf(var + BN_EPS);
    bnscale[c] = sc;
    bnshift[c] = fmaf(-mu, sc, beta[c]);
  }
}

// ================================================================== launcher
extern "C" void kernel_launch(void* const* d_in, const int* in_sizes, int n_in,
                              void* d_out, int out_size, void* d_ws, size_t ws_size,
                              hipStream_t stream) {
  const float* x      = (const float*)d_in[0];
  const float* embW   = (const float*)d_in[1];
  const float* embB   = (const float*)d_in[2];
  const float* preW1  = (const float*)d_in[3];
  const float* preb1  = (const float*)d_in[4];
  const float* postW1 = (const float*)d_in[5];
  const float* postb1 = (const float*)d_in[6];
  const float* linW1  = (const float*)d_in[7];
  const float* linb1  = (const float*)d_in[8];
  const float* gamma  = (const float*)d_in[9];
  const float* beta   = (const float*)d_in[10];
  const float* preW2  = (const float*)d_in[11];
  const float* preb2  = (const float*)d_in[12];
  const float* postW2 = (const float*)d_in[13];
  const float* postb2 = (const float*)d_in[14];
  const float* linW2  = (const float*)d_in[15];
  const float* linb2  = (const float*)d_in[16];
  const int*   src    = (const int*)d_in[17];
  const int*   dst    = (const int*)d_in[18];
  float* out = (float*)d_out;

  char* w = (char*)d_ws;
  size_t o = 0;
  int*   deg     = (int*)(w + o);   o += (size_t)N_NODES * 4;
  float* scalars = (float*)(w + o); o += 64;
  float* bnsum   = (float*)(w + o); o += 256;
  float* bnsumsq = (float*)(w + o); o += 256;
  float* bnscale = (float*)(w + o); o += 256;
  float* bnshift = (float*)(w + o); o += 256;
  size_t zero_len = o;
  o = (o + 255) & ~(size_t)255;
  int* partials = (int*)(w + o);  o += 256;
  int* row_ptr  = (int*)(w + o);  o += (size_t)(N_NODES + 1) * 4; o = (o + 255) & ~(size_t)255;
  int* cursor   = (int*)(w + o);  o += (size_t)N_NODES * 4;       o = (o + 255) & ~(size_t)255;
  int* csr      = (int*)(w + o);  o += (size_t)E_EDGES * 4;       o = (o + 255) & ~(size_t)255;
  float* h1 = (float*)(w + o); o += (size_t)N_NODES * 64 * 4;
  float* y1 = (float*)(w + o); o += (size_t)N_NODES * 64 * 4;
  float* h2 = (float*)(w + o); o += (size_t)N_NODES * 64 * 4;
  float* hA = (float*)(w + o); o += (size_t)N_NODES * 128 * 4;
  float* hB = (float*)(w + o); o += (size_t)N_NODES * 128 * 4;

  hipMemsetAsync(w, 0, zero_len, stream);

  const int NBLK_SCAN = (N_NODES + 1023) / 1024;   // 49
  k_hist<<<(E_EDGES + 255) / 256, 256, 0, stream>>>(dst, deg);
  k_sumlog<<<(N_NODES + 255) / 256, 256, 0, stream>>>(deg, scalars);
  k_scan_part<<<NBLK_SCAN, 256, 0, stream>>>(deg, partials);
  k_scan_mid<<<1, 64, 0, stream>>>(partials, NBLK_SCAN, scalars);
  k_scan_final<<<NBLK_SCAN, 256, 0, stream>>>(deg, partials, row_ptr, cursor);
  k_scatter<<<(E_EDGES + 255) / 256, 256, 0, stream>>>(src, dst, cursor, csr);

  k_embed<<<768, 256, 0, stream>>>(x, embW, embB, h1);

  // ----- layer 1
  k_preab<false><<<768, 256, 0, stream>>>(h1, preW1, preb1, nullptr, nullptr, nullptr, hA, hB);
  k_conv<<<N_NODES / 16, 256, 0, stream>>>(hA, hB, h1, row_ptr, csr,
                                           postW1, postb1, linW1, linb1, scalars, y1);
  // ----- batchnorm
  k_bnstats<<<256, 256, 0, stream>>>(y1, bnsum, bnsumsq);
  k_bnfin<<<1, 64, 0, stream>>>(bnsum, bnsumsq, gamma, beta, bnscale, bnshift);

  // ----- layer 2 (BN+relu fused into staging; h2 materialized for skip)
  k_preab<true><<<768, 256, 0, stream>>>(y1, preW2, preb2, bnscale, bnshift, h2, hA, hB);
  k_conv<<<N_NODES / 16, 256, 0, stream>>>(hA, hB, h2, row_ptr, csr,
                                           postW2, postb2, linW2, linb2, scalars, out);
}

// Round 7
// 553.483 us; speedup vs baseline: 1.8121x; 1.0377x over previous
//
#include <hip/hip_runtime.h>

#define N_NODES 50000
#define E_EDGES 800000
#define IN_F    128
#define H_F     64
#define STD_EPS 1e-5f
#define BN_EPS  1e-5f

// ---------------------------------------------------------------- degree hist
__global__ __launch_bounds__(256) void k_hist(const int* __restrict__ dst,
                                              int* __restrict__ deg) {
  int e = blockIdx.x * 256 + threadIdx.x;
  if (e < E_EDGES) atomicAdd(&deg[dst[e]], 1);
}

// ---------------------------------------- scan phase 1 + fused sum(log(deg+1))
__global__ __launch_bounds__(256) void k_scan_part(const int* __restrict__ deg,
                                                   int* __restrict__ partials,
                                                   float* __restrict__ scalars) {
  __shared__ int red[256];
  __shared__ float redf[256];
  int base = blockIdx.x * 1024;
  int s = 0; float ls = 0.f;
  for (int j = threadIdx.x; j < 1024; j += 256) {
    int i = base + j;
    if (i < N_NODES) { int d = deg[i]; s += d; ls += logf((float)d + 1.0f); }
  }
  red[threadIdx.x] = s; redf[threadIdx.x] = ls; __syncthreads();
  for (int st = 128; st > 0; st >>= 1) {
    if (threadIdx.x < st) {
      red[threadIdx.x] += red[threadIdx.x + st];
      redf[threadIdx.x] += redf[threadIdx.x + st];
    }
    __syncthreads();
  }
  if (threadIdx.x == 0) {
    partials[blockIdx.x] = red[0];
    atomicAdd(&scalars[0], redf[0]);
  }
}

__global__ void k_scan_mid(int* __restrict__ partials, int nblk,
                           float* __restrict__ scalars) {
  if (threadIdx.x == 0) {
    int run = 0;
    for (int b = 0; b < nblk; b++) { int v = partials[b]; partials[b] = run; run += v; }
    scalars[1] = scalars[0] / (float)N_NODES;   // avg_log
  }
}

__global__ __launch_bounds__(256) void k_scan_final(const int* __restrict__ deg,
                                                    const int* __restrict__ partials,
                                                    int* __restrict__ row_ptr,
                                                    int* __restrict__ cursor) {
  __shared__ int ts[256];
  int base = blockIdx.x * 1024 + threadIdx.x * 4;
  int d[4]; int s = 0;
#pragma unroll
  for (int j = 0; j < 4; j++) {
    int i = base + j;
    d[j] = (i < N_NODES) ? deg[i] : 0;
    s += d[j];
  }
  ts[threadIdx.x] = s; __syncthreads();
  for (int off = 1; off < 256; off <<= 1) {
    int t = (threadIdx.x >= off) ? ts[threadIdx.x - off] : 0;
    __syncthreads();
    ts[threadIdx.x] += t;
    __syncthreads();
  }
  int excl = (threadIdx.x > 0) ? ts[threadIdx.x - 1] : 0;
  int run = partials[blockIdx.x] + excl;
#pragma unroll
  for (int j = 0; j < 4; j++) {
    int i = base + j;
    if (i < N_NODES) { row_ptr[i] = run; cursor[i] = run; run += d[j]; }
  }
  if (blockIdx.x == 0 && threadIdx.x == 0) row_ptr[N_NODES] = E_EDGES;
}

// ------------------------------------------------------------------- scatter
__global__ __launch_bounds__(256) void k_scatter(const int* __restrict__ src,
                                                 const int* __restrict__ dst,
                                                 int* __restrict__ cursor,
                                                 int* __restrict__ csr_src) {
  int e = blockIdx.x * 256 + threadIdx.x;
  if (e < E_EDGES) {
    int d = dst[e];
    int p = atomicAdd(&cursor[d], 1);
    csr_src[p] = src[e];
  }
}

// --------------------------------------------------------------------- embed
__global__ __launch_bounds__(256) void k_embed(const float* __restrict__ x,
                                               const float* __restrict__ W,
                                               const float* __restrict__ bias,
                                               float* __restrict__ h) {
  __shared__ float sW[IN_F * 64];    // 32 KB
  __shared__ float sx[IN_F * 20];    // x_T[k][16+pad4]
  for (int i = threadIdx.x; i < IN_F * 64; i += 256) sW[i] = W[i];
  int j = threadIdx.x & 63, ng = threadIdx.x >> 6;
  float bj = bias[j];
  for (int grp = blockIdx.x; grp < N_NODES / 16; grp += gridDim.x) {
    int n0 = grp * 16;
    __syncthreads();
    for (int idx = threadIdx.x; idx < 16 * IN_F; idx += 256) {
      int nl = idx >> 7, k = idx & 127;
      sx[k * 20 + nl] = x[(size_t)(n0 + nl) * IN_F + k];
    }
    __syncthreads();
    float a0 = bj, a1 = bj, a2 = bj, a3 = bj;
    const float* xp = &sx[ng * 4];
#pragma unroll 4
    for (int k = 0; k < IN_F; k++) {
      float4 xv = *(const float4*)&xp[k * 20];
      float w = sW[k * 64 + j];
      a0 = fmaf(xv.x, w, a0); a1 = fmaf(xv.y, w, a1);
      a2 = fmaf(xv.z, w, a2); a3 = fmaf(xv.w, w, a3);
    }
    size_t ob = (size_t)(n0 + ng * 4) * 64 + j;
    h[ob] = a0; h[ob + 64] = a1; h[ob + 128] = a2; h[ob + 192] = a3;
  }
}

// ------------------------------------------------------------------ pre A/B
// One TOWER per block (t = blockIdx.x & 1).  32-node groups, 8 nodes/thread.
// Weights packed interleaved: sWp[k*128 + f*2 + {0,1}] = {Wa[k,f], Wb[k,f]}
//   -> k-loop reads ONE b64 weight + TWO broadcast b128 h-reads per 16 FMA.
template <bool BN>
__global__ __launch_bounds__(256) void k_preab(const float* __restrict__ hin,
                                               const float* __restrict__ preW,
                                               const float* __restrict__ preb,
                                               const float* __restrict__ bnscale,
                                               const float* __restrict__ bnshift,
                                               float* __restrict__ h2out,
                                               float* __restrict__ hA,
                                               float* __restrict__ hB) {
  __shared__ float sWp[64 * 128];   // 32 KB packed [k][f][{A,B}]
  __shared__ float sh[64 * 36];     // h_T[k][32+pad4]  9216 B
  int t = blockIdx.x & 1;
  const float* Wsrc = preW + (size_t)t * 128 * 64;
  for (int i = threadIdx.x; i < 64 * 64; i += 256) {
    int k = i >> 6, f = i & 63;
    float wa = Wsrc[k * 64 + f];
    float wb = Wsrc[(64 + k) * 64 + f];
    *(float2*)&sWp[k * 128 + f * 2] = make_float2(wa, wb);
  }
  int f = threadIdx.x & 63, ng = threadIdx.x >> 6;   // ng 0..3 -> 8 nodes each
  float pb = preb[t * 64 + f];
  int nblk2 = gridDim.x >> 1;
  const int NGRP = (N_NODES + 31) / 32;   // 1563
  for (int grp = blockIdx.x >> 1; grp < NGRP; grp += nblk2) {
    int n0 = grp * 32;
    __syncthreads();
    for (int idx = threadIdx.x; idx < 32 * 64; idx += 256) {
      int nl = idx >> 6, k = idx & 63;
      int n = n0 + nl;
      float v = 0.f;
      if (n < N_NODES) {
        v = hin[(size_t)n * 64 + k];
        if (BN) {
          v = fmaxf(fmaf(v, bnscale[k], bnshift[k]), 0.f);
          if (t == 0) h2out[(size_t)n * 64 + k] = v;
        }
      }
      sh[k * 36 + nl] = v;
    }
    __syncthreads();
    float a[8] = {pb, pb, pb, pb, pb, pb, pb, pb};
    float b[8] = {0, 0, 0, 0, 0, 0, 0, 0};
    const float* hp = &sh[ng * 8];
    const float* wp = &sWp[f * 2];
#pragma unroll 4
    for (int k = 0; k < 64; k++) {
      float4 h0 = *(const float4*)&hp[k * 36];
      float4 h1 = *(const float4*)&hp[k * 36 + 4];
      float2 w2 = *(const float2*)&wp[k * 128];
      a[0] = fmaf(h0.x, w2.x, a[0]); b[0] = fmaf(h0.x, w2.y, b[0]);
      a[1] = fmaf(h0.y, w2.x, a[1]); b[1] = fmaf(h0.y, w2.y, b[1]);
      a[2] = fmaf(h0.z, w2.x, a[2]); b[2] = fmaf(h0.z, w2.y, b[2]);
      a[3] = fmaf(h0.w, w2.x, a[3]); b[3] = fmaf(h0.w, w2.y, b[3]);
      a[4] = fmaf(h1.x, w2.x, a[4]); b[4] = fmaf(h1.x, w2.y, b[4]);
      a[5] = fmaf(h1.y, w2.x, a[5]); b[5] = fmaf(h1.y, w2.y, b[5]);
      a[6] = fmaf(h1.z, w2.x, a[6]); b[6] = fmaf(h1.z, w2.y, b[6]);
      a[7] = fmaf(h1.w, w2.x, a[7]); b[7] = fmaf(h1.w, w2.y, b[7]);
    }
    int tf = t * 64 + f;
#pragma unroll
    for (int j = 0; j < 8; j++) {
      int n = n0 + ng * 8 + j;
      if (n < N_NODES) {
        hA[(size_t)n * 128 + tf] = a[j];
        hB[(size_t)n * 128 + tf] = b[j];
      }
    }
  }
}

// --------------------------------------------------- fused conv main kernel
// R5 shape: 8 nodes/block, 20.5 KB LDS, now __launch_bounds__(256,7)
//   -> 7 blocks/CU (7 x 20480 = 143 KB < 160 KB), 28 waves/CU.
// LDS: 5 unique slices [t][feat5][node8][hf64]; factored G1,G2,G3 combined
// as G1 + sA*G2 + sB*G3. postW in original [f13*32+g] layout (coalesced).
__global__ __launch_bounds__(256, 7) void k_conv(const float* __restrict__ hA,
                                                 const float* __restrict__ hB,
                                                 const float* __restrict__ hskip,
                                                 const int* __restrict__ row_ptr,
                                                 const int* __restrict__ csr_src,
                                                 const float* __restrict__ postW,
                                                 const float* __restrict__ postb,
                                                 const float* __restrict__ linW,
                                                 const float* __restrict__ linb,
                                                 const float* __restrict__ scalars,
                                                 float* __restrict__ out) {
  __shared__ float sm[2 * 5 * 8 * 64];   // 20480 B; [(t*5+feat)*512 + node*64 + hf]
  __shared__ float sAB[16];              // sA[0..7], sB[8..15]
  int w = threadIdx.x >> 6, lane = threadIdx.x & 63;
  int n0 = blockIdx.x * 8;
  int t = lane >> 5, fb = (lane & 31) * 2;
  int off = t * 64 + fb;
  float avg = scalars[1];

  // ---- phase A: aggregation, 2 nodes per wave, 4 loads in flight
#pragma unroll 1
  for (int k = 0; k < 2; k++) {
    int nl = w * 2 + k;
    int n = n0 + nl;
    float2 a = *(const float2*)&hA[(size_t)n * 128 + off];
    int rp0 = __builtin_amdgcn_readfirstlane(row_ptr[n]);
    int rp1 = __builtin_amdgcn_readfirstlane(row_ptr[n + 1]);
    float sx0=0,sy0=0,qx0=0,qy0=0, sx1=0,sy1=0,qx1=0,qy1=0;
    float mnx0=INFINITY,mny0=INFINITY,mxx0=-INFINITY,mxy0=-INFINITY;
    float mnx1=INFINITY,mny1=INFINITY,mxx1=-INFINITY,mxy1=-INFINITY;
    int i = rp0;
    int end4 = rp0 + ((rp1 - rp0) & ~3);
    if (i < end4) {
      int s0 = csr_src[i], s1 = csr_src[i+1], s2 = csr_src[i+2], s3 = csr_src[i+3];
      while (true) {
        float2 v0 = *(const float2*)&hB[(size_t)s0 * 128 + off];
        float2 v1 = *(const float2*)&hB[(size_t)s1 * 128 + off];
        float2 v2 = *(const float2*)&hB[(size_t)s2 * 128 + off];
        float2 v3 = *(const float2*)&hB[(size_t)s3 * 128 + off];
        i += 4;
        bool more = (i < end4);
        if (more) { s0 = csr_src[i]; s1 = csr_src[i+1]; s2 = csr_src[i+2]; s3 = csr_src[i+3]; }
        float e0x = v0.x + a.x, e0y = v0.y + a.y;
        float e1x = v1.x + a.x, e1y = v1.y + a.y;
        float e2x = v2.x + a.x, e2y = v2.y + a.y;
        float e3x = v3.x + a.x, e3y = v3.y + a.y;
        sx0 += e0x; qx0 = fmaf(e0x,e0x,qx0); mnx0 = fminf(mnx0,e0x); mxx0 = fmaxf(mxx0,e0x);
        sy0 += e0y; qy0 = fmaf(e0y,e0y,qy0); mny0 = fminf(mny0,e0y); mxy0 = fmaxf(mxy0,e0y);
        sx1 += e1x; qx1 = fmaf(e1x,e1x,qx1); mnx1 = fminf(mnx1,e1x); mxx1 = fmaxf(mxx1,e1x);
        sy1 += e1y; qy1 = fmaf(e1y,e1y,qy1); mny1 = fminf(mny1,e1y); mxy1 = fmaxf(mxy1,e1y);
        sx0 += e2x; qx0 = fmaf(e2x,e2x,qx0); mnx0 = fminf(mnx0,e2x); mxx0 = fmaxf(mxx0,e2x);
        sy0 += e2y; qy0 = fmaf(e2y,e2y,qy0); mny0 = fminf(mny0,e2y); mxy0 = fmaxf(mxy0,e2y);
        sx1 += e3x; qx1 = fmaf(e3x,e3x,qx1); mnx1 = fminf(mnx1,e3x); mxx1 = fmaxf(mxx1,e3x);
        sy1 += e3y; qy1 = fmaf(e3y,e3y,qy1); mny1 = fminf(mny1,e3y); mxy1 = fmaxf(mxy1,e3y);
        if (!more) break;
      }
    }
    {   // masked tail: 0..3 edges, all loads issued together
      int r = rp1 - i;
      if (r > 0) {
        int e1i = (r > 1) ? i + 1 : i;
        int e2i = (r > 2) ? i + 2 : i;
        int t0 = csr_src[i], t1 = csr_src[e1i], t2 = csr_src[e2i];
        float2 u0 = *(const float2*)&hB[(size_t)t0 * 128 + off];
        float2 u1 = *(const float2*)&hB[(size_t)t1 * 128 + off];
        float2 u2 = *(const float2*)&hB[(size_t)t2 * 128 + off];
        float ex = u0.x + a.x, ey = u0.y + a.y;
        sx0 += ex; qx0 = fmaf(ex,ex,qx0); mnx0 = fminf(mnx0,ex); mxx0 = fmaxf(mxx0,ex);
        sy0 += ey; qy0 = fmaf(ey,ey,qy0); mny0 = fminf(mny0,ey); mxy0 = fmaxf(mxy0,ey);
        if (r > 1) {
          ex = u1.x + a.x; ey = u1.y + a.y;
          sx1 += ex; qx1 = fmaf(ex,ex,qx1); mnx1 = fminf(mnx1,ex); mxx1 = fmaxf(mxx1,ex);
          sy1 += ey; qy1 = fmaf(ey,ey,qy1); mny1 = fminf(mny1,ey); mxy1 = fmaxf(mxy1,ey);
        }
        if (r > 2) {
          ex = u2.x + a.x; ey = u2.y + a.y;
          sx0 += ex; qx0 = fmaf(ex,ex,qx0); mnx0 = fminf(mnx0,ex); mxx0 = fmaxf(mxx0,ex);
          sy0 += ey; qy0 = fmaf(ey,ey,qy0); mny0 = fminf(mny0,ey); mxy0 = fmaxf(mxy0,ey);
        }
      }
    }
    int dg = rp1 - rp0;
    float cnt = (float)(dg > 0 ? dg : 1);
    float inv = 1.0f / cnt;
    float meanx = (sx0 + sx1) * inv, meany = (sy0 + sy1) * inv;
    float qx = qx0 + qx1, qy = qy0 + qy1;
    float sdx = sqrtf(fmaxf(qx * inv - meanx * meanx, 0.f) + STD_EPS);
    float sdy = sqrtf(fmaxf(qy * inv - meany * meany, 0.f) + STD_EPS);
    float mnx = fminf(mnx0, mnx1), mny = fminf(mny0, mny1);
    float mxx = fmaxf(mxx0, mxx1), mxy = fmaxf(mxy0, mxy1);
    if (dg == 0) { mnx = 0; mny = 0; mxx = 0; mxy = 0; }
    float ldv = logf(cnt + 1.f);
    float2 hsv = *(const float2*)&hskip[(size_t)n * 64 + fb];
    // write 5 unique slices
    float* bp = &sm[t * 2560 + nl * 64 + fb];
    *(float2*)&bp[0]    = hsv;
    *(float2*)&bp[512]  = make_float2(meanx, meany);
    *(float2*)&bp[1024] = make_float2(mnx, mny);
    *(float2*)&bp[1536] = make_float2(mxx, mxy);
    *(float2*)&bp[2048] = make_float2(sdx, sdy);
    if (lane == 0) { sAB[nl] = ldv / avg; sAB[8 + nl] = avg / ldv; }
  }
  __syncthreads();

  // ---- phase C: factored post matmul; wave w covers hf [w*16, w*16+16)
  float g1[8] = {0,0,0,0,0,0,0,0};
  float g2[8] = {0,0,0,0,0,0,0,0};
  float g3[8] = {0,0,0,0,0,0,0,0};
  {
    int g = lane & 31, hf0 = w * 16;
    const float* pw = &postW[(size_t)t * (832 * 32) + g];   // [f13*32 + g]
    const float* vb = &sm[t * 2560 + hf0];
    // feat0 = h (f13 = hf): G1 only
#pragma unroll
    for (int j = 0; j < 16; j += 4) {
      int f13 = hf0 + j;
      float w0 = pw[f13 * 32],       w1 = pw[(f13 + 1) * 32];
      float w2 = pw[(f13 + 2) * 32], w3 = pw[(f13 + 3) * 32];
#pragma unroll
      for (int nn = 0; nn < 8; nn++) {
        float4 v = *(const float4*)&vb[nn * 64 + j];
        g1[nn] = fmaf(v.w, w3, fmaf(v.z, w2, fmaf(v.y, w1, fmaf(v.x, w0, g1[nn]))));
      }
    }
    // feats 1..4 (agg): G1 at f13=64+fa*64+hf, G2 at +256, G3 at +512
#pragma unroll
    for (int fa = 0; fa < 4; fa++) {
      const float* vfa = &vb[(1 + fa) * 512];
#pragma unroll
      for (int j = 0; j < 16; j += 4) {
        int f13 = 64 + fa * 64 + hf0 + j;
        float w10 = pw[f13 * 32],         w11 = pw[(f13 + 1) * 32];
        float w12 = pw[(f13 + 2) * 32],   w13 = pw[(f13 + 3) * 32];
        float w20 = pw[(f13 + 256) * 32], w21 = pw[(f13 + 257) * 32];
        float w22 = pw[(f13 + 258) * 32], w23 = pw[(f13 + 259) * 32];
        float w30 = pw[(f13 + 512) * 32], w31 = pw[(f13 + 513) * 32];
        float w32 = pw[(f13 + 514) * 32], w33 = pw[(f13 + 515) * 32];
#pragma unroll
        for (int nn = 0; nn < 8; nn++) {
          float4 v = *(const float4*)&vfa[nn * 64 + j];
          g1[nn] = fmaf(v.w, w13, fmaf(v.z, w12, fmaf(v.y, w11, fmaf(v.x, w10, g1[nn]))));
          g2[nn] = fmaf(v.w, w23, fmaf(v.z, w22, fmaf(v.y, w21, fmaf(v.x, w20, g2[nn]))));
          g3[nn] = fmaf(v.w, w33, fmaf(v.z, w32, fmaf(v.y, w31, fmaf(v.x, w30, g3[nn]))));
        }
      }
    }
  }
  // combine with per-node scalars (sAB reads are broadcast)
  float o8[8];
#pragma unroll
  for (int nn = 0; nn < 8; nn++)
    o8[nn] = fmaf(sAB[8 + nn], g3[nn], fmaf(sAB[nn], g2[nn], g1[nn]));
  __syncthreads();   // all sm reads done -> safe to alias

  // ---- partials into aliased region: lpart[node8][tg64][rep4] = sm[0..2047]
  {
    int sw = (w + (lane >> 4)) & 3;
#pragma unroll
    for (int nn = 0; nn < 8; nn++)
      sm[((nn * 64 + lane) << 2) + sw] = o8[nn];
  }
  __syncthreads();

  // ---- reduce + postb -> po at sm[2048 + node*64 + col]
  {
#pragma unroll
    for (int r = 0; r < 2; r++) {
      int idx = r * 256 + (int)threadIdx.x;
      float4 p = *(const float4*)&sm[idx << 2];
      sm[2048 + idx] = p.x + p.y + p.z + p.w + postb[idx & 63];
    }
  }
  __syncthreads();

  // ---- lin epilogue: wave w -> nodes w*2, w*2+1; col = lane
  {
    float acc0 = linb[lane], acc1 = acc0;
    const float* lw = linW + lane;
    const float* p0 = &sm[2048 + (w * 2) * 64];
    const float* p1 = p0 + 64;
#pragma unroll
    for (int c = 0; c < 64; c += 4) {
      float lw0 = lw[c * 64], lw1 = lw[(c + 1) * 64];
      float lw2 = lw[(c + 2) * 64], lw3 = lw[(c + 3) * 64];
      float4 pa = *(const float4*)&p0[c];
      float4 pb2 = *(const float4*)&p1[c];
      acc0 = fmaf(pa.w, lw3, fmaf(pa.z, lw2, fmaf(pa.y, lw1, fmaf(pa.x, lw0, acc0))));
      acc1 = fmaf(pb2.w, lw3, fmaf(pb2.z, lw2, fmaf(pb2.y, lw1, fmaf(pb2.x, lw0, acc1))));
    }
    size_t ob = (size_t)(n0 + w * 2) * 64 + lane;
    out[ob] = acc0;
    out[ob + 64] = acc1;
  }
}

// ------------------------------------------------------------------ BN stats
__global__ __launch_bounds__(256) void k_bnstats(const float* __restrict__ y,
                                                 float* __restrict__ bnsum,
                                                 float* __restrict__ bnsumsq) {
  __shared__ float r1[256], r2[256];
  int c = threadIdx.x & 63, r = threadIdx.x >> 6;
  float s = 0, q = 0;
  for (int n = blockIdx.x * 4 + r; n < N_NODES; n += gridDim.x * 4) {
    float v = y[(size_t)n * 64 + c];
    s += v; q = fmaf(v, v, q);
  }
  r1[threadIdx.x] = s; r2[threadIdx.x] = q; __syncthreads();
  if (threadIdx.x < 64) {
    s = r1[threadIdx.x] + r1[threadIdx.x + 64] + r1[threadIdx.x + 128] + r1[threadIdx.x + 192];
    q = r2[threadIdx.x] + r2[threadIdx.x + 64] + r2[threadIdx.x + 128] + r2[threadIdx.x + 192];
    atomicAdd(&bnsum[threadIdx.x], s);
    atomicAdd(&bnsumsq[threadIdx.x], q);
  }
}

__global__ void k_bnfin(const float* __restrict__ bnsum, const float* __restrict__ bnsumsq,
                        const float* __restrict__ gamma, const float* __restrict__ beta,
                        float* __restrict__ bnscale, float* __restrict__ bnshift) {
  int c = threadIdx.x;
  if (c < 64) {
    float mu = bnsum[c] * (1.f / N_NODES);
    float var = bnsumsq[c] * (1.f / N_NODES) - mu * mu;
    float sc = gamma[c] / sqrtf(var + BN_EPS);
    bnscale[c] = sc;
    bnshift[c] = fmaf(-mu, sc, beta[c]);
  }
}

// ================================================================== launcher
extern "C" void kernel_launch(void* const* d_in, const int* in_sizes, int n_in,
                              void* d_out, int out_size, void* d_ws, size_t ws_size,
                              hipStream_t stream) {
  const float* x      = (const float*)d_in[0];
  const float* embW   = (const float*)d_in[1];
  const float* embB   = (const float*)d_in[2];
  const float* preW1  = (const float*)d_in[3];
  const float* preb1  = (const float*)d_in[4];
  const float* postW1 = (const float*)d_in[5];
  const float* postb1 = (const float*)d_in[6];
  const float* linW1  = (const float*)d_in[7];
  const float* linb1  = (const float*)d_in[8];
  const float* gamma  = (const float*)d_in[9];
  const float* beta   = (const float*)d_in[10];
  const float* preW2  = (const float*)d_in[11];
  const float* preb2  = (const float*)d_in[12];
  const float* postW2 = (const float*)d_in[13];
  const float* postb2 = (const float*)d_in[14];
  const float* linW2  = (const float*)d_in[15];
  const float* linb2  = (const float*)d_in[16];
  const int*   src    = (const int*)d_in[17];
  const int*   dst    = (const int*)d_in[18];
  float* out = (float*)d_out;

  char* w = (char*)d_ws;
  size_t o = 0;
  int*   deg     = (int*)(w + o);   o += (size_t)N_NODES * 4;
  float* scalars = (float*)(w + o); o += 64;
  float* bnsum   = (float*)(w + o); o += 256;
  float* bnsumsq = (float*)(w + o); o += 256;
  float* bnscale = (float*)(w + o); o += 256;
  float* bnshift = (float*)(w + o); o += 256;
  size_t zero_len = o;
  o = (o + 255) & ~(size_t)255;
  int* partials = (int*)(w + o);  o += 256;
  int* row_ptr  = (int*)(w + o);  o += (size_t)(N_NODES + 1) * 4; o = (o + 255) & ~(size_t)255;
  int* cursor   = (int*)(w + o);  o += (size_t)N_NODES * 4;       o = (o + 255) & ~(size_t)255;
  int* csr      = (int*)(w + o);  o += (size_t)E_EDGES * 4;       o = (o + 255) & ~(size_t)255;
  float* h1 = (float*)(w + o); o += (size_t)N_NODES * 64 * 4;
  float* y1 = (float*)(w + o); o += (size_t)N_NODES * 64 * 4;
  float* h2 = (float*)(w + o); o += (size_t)N_NODES * 64 * 4;
  float* hA = (float*)(w + o); o += (size_t)N_NODES * 128 * 4;
  float* hB = (float*)(w + o); o += (size_t)N_NODES * 128 * 4;

  hipMemsetAsync(w, 0, zero_len, stream);

  const int NBLK_SCAN = (N_NODES + 1023) / 1024;   // 49
  k_hist<<<(E_EDGES + 255) / 256, 256, 0, stream>>>(dst, deg);
  k_scan_part<<<NBLK_SCAN, 256, 0, stream>>>(deg, partials, scalars);
  k_scan_mid<<<1, 64, 0, stream>>>(partials, NBLK_SCAN, scalars);
  k_scan_final<<<NBLK_SCAN, 256, 0, stream>>>(deg, partials, row_ptr, cursor);
  k_scatter<<<(E_EDGES + 255) / 256, 256, 0, stream>>>(src, dst, cursor, csr);

  k_embed<<<768, 256, 0, stream>>>(x, embW, embB, h1);

  // ----- layer 1
  k_preab<false><<<768, 256, 0, stream>>>(h1, preW1, preb1, nullptr, nullptr, nullptr, hA, hB);
  k_conv<<<N_NODES / 8, 256, 0, stream>>>(hA, hB, h1, row_ptr, csr,
                                          postW1, postb1, linW1, linb1, scalars, y1);
  // ----- batchnorm
  k_bnstats<<<256, 256, 0, stream>>>(y1, bnsum, bnsumsq);
  k_bnfin<<<1, 64, 0, stream>>>(bnsum, bnsumsq, gamma, beta, bnscale, bnshift);

  // ----- layer 2 (BN+relu fused into staging; h2 materialized for skip)
  k_preab<true><<<768, 256, 0, stream>>>(y1, preW2, preb2, bnscale, bnshift, h2, hA, hB);
  k_conv<<<N_NODES / 8, 256, 0, stream>>>(hA, hB, h2, row_ptr, csr,
                                          postW2, postb2, linW2, linb2, scalars, out);
}

// Round 8
// 544.044 us; speedup vs baseline: 1.8436x; 1.0173x over previous
//
#include <hip/hip_runtime.h>

#define N_NODES 50000
#define E_EDGES 800000
#define IN_F    128
#define H_F     64
#define STD_EPS 1e-5f
#define BN_EPS  1e-5f

// ---------------------------------------------------------------- degree hist
__global__ __launch_bounds__(256) void k_hist(const int* __restrict__ dst,
                                              int* __restrict__ deg) {
  int e = blockIdx.x * 256 + threadIdx.x;
  if (e < E_EDGES) atomicAdd(&deg[dst[e]], 1);
}

// ---------------------------------------- scan phase 1 + fused sum(log(deg+1))
__global__ __launch_bounds__(256) void k_scan_part(const int* __restrict__ deg,
                                                   int* __restrict__ partials,
                                                   float* __restrict__ scalars) {
  __shared__ int red[256];
  __shared__ float redf[256];
  int base = blockIdx.x * 1024;
  int s = 0; float ls = 0.f;
  for (int j = threadIdx.x; j < 1024; j += 256) {
    int i = base + j;
    if (i < N_NODES) { int d = deg[i]; s += d; ls += logf((float)d + 1.0f); }
  }
  red[threadIdx.x] = s; redf[threadIdx.x] = ls; __syncthreads();
  for (int st = 128; st > 0; st >>= 1) {
    if (threadIdx.x < st) {
      red[threadIdx.x] += red[threadIdx.x + st];
      redf[threadIdx.x] += redf[threadIdx.x + st];
    }
    __syncthreads();
  }
  if (threadIdx.x == 0) {
    partials[blockIdx.x] = red[0];
    atomicAdd(&scalars[0], redf[0]);
  }
}

__global__ void k_scan_mid(int* __restrict__ partials, int nblk,
                           float* __restrict__ scalars) {
  if (threadIdx.x == 0) {
    int run = 0;
    for (int b = 0; b < nblk; b++) { int v = partials[b]; partials[b] = run; run += v; }
    scalars[1] = scalars[0] / (float)N_NODES;   // avg_log
  }
}

__global__ __launch_bounds__(256) void k_scan_final(const int* __restrict__ deg,
                                                    const int* __restrict__ partials,
                                                    int* __restrict__ row_ptr,
                                                    int* __restrict__ cursor) {
  __shared__ int ts[256];
  int base = blockIdx.x * 1024 + threadIdx.x * 4;
  int d[4]; int s = 0;
#pragma unroll
  for (int j = 0; j < 4; j++) {
    int i = base + j;
    d[j] = (i < N_NODES) ? deg[i] : 0;
    s += d[j];
  }
  ts[threadIdx.x] = s; __syncthreads();
  for (int off = 1; off < 256; off <<= 1) {
    int t = (threadIdx.x >= off) ? ts[threadIdx.x - off] : 0;
    __syncthreads();
    ts[threadIdx.x] += t;
    __syncthreads();
  }
  int excl = (threadIdx.x > 0) ? ts[threadIdx.x - 1] : 0;
  int run = partials[blockIdx.x] + excl;
#pragma unroll
  for (int j = 0; j < 4; j++) {
    int i = base + j;
    if (i < N_NODES) { row_ptr[i] = run; cursor[i] = run; run += d[j]; }
  }
  if (blockIdx.x == 0 && threadIdx.x == 0) row_ptr[N_NODES] = E_EDGES;
}

// ------------------------------------------------------------------- scatter
__global__ __launch_bounds__(256) void k_scatter(const int* __restrict__ src,
                                                 const int* __restrict__ dst,
                                                 int* __restrict__ cursor,
                                                 int* __restrict__ csr_src) {
  int e = blockIdx.x * 256 + threadIdx.x;
  if (e < E_EDGES) {
    int d = dst[e];
    int p = atomicAdd(&cursor[d], 1);
    csr_src[p] = src[e];
  }
}

// ------------------------------------------- packed weight transpose (1-off)
// postWT[layer][t][fb=f13/4][g][4j]: flat = layer*53248 + t*26624 + fb*128 + g*4 + j
//   src = postW_layer[t*26624 + (fb*4+j)*32 + g]
// linWT[layer][c4][col][4j]: flat = layer*4096 + c4*256 + col*4 + j
//   src = linW_layer[(c4*4+j)*64 + col]
// -> in-kernel: lane g reads dwordx4 = 4 consecutive-f13 weights, coalesced.
__global__ __launch_bounds__(256) void k_transpose(const float* __restrict__ pW1,
                                                   const float* __restrict__ pW2,
                                                   const float* __restrict__ lW1,
                                                   const float* __restrict__ lW2,
                                                   float* __restrict__ pWT,
                                                   float* __restrict__ lWT) {
  int idx = blockIdx.x * 256 + threadIdx.x;
  if (idx < 106496) {
    int layer = idx / 53248, r = idx % 53248;
    int t = r / 26624, r2 = r % 26624;
    int fb = r2 / 128, r3 = r2 % 128;
    int g = r3 / 4, j = r3 % 4;
    const float* srcp = layer ? pW2 : pW1;
    pWT[idx] = srcp[(size_t)t * 26624 + (fb * 4 + j) * 32 + g];
  } else if (idx < 114688) {
    int jj = idx - 106496;
    int layer = jj / 4096, r2 = jj % 4096;
    int c4 = r2 / 256, r3 = r2 % 256;
    int col = r3 / 4, j = r3 % 4;
    const float* srcl = layer ? lW2 : lW1;
    lWT[jj] = srcl[(c4 * 4 + j) * 64 + col];
  }
}

// --------------------------------------------------------------------- embed
// 32-node groups, 8 nodes/thread (k_preab-proven shape).
__global__ __launch_bounds__(256) void k_embed(const float* __restrict__ x,
                                               const float* __restrict__ W,
                                               const float* __restrict__ bias,
                                               float* __restrict__ h) {
  __shared__ float sW[IN_F * 64];    // 32 KB
  __shared__ float sx[IN_F * 36];    // x_T[k][32+pad4] 18 KB
  for (int i = threadIdx.x; i < IN_F * 64; i += 256) sW[i] = W[i];
  int f = threadIdx.x & 63, ng = threadIdx.x >> 6;   // ng 0..3 -> 8 nodes each
  float bj = bias[f];
  const int NGRP = (N_NODES + 31) / 32;   // 1563
  for (int grp = blockIdx.x; grp < NGRP; grp += gridDim.x) {
    int n0 = grp * 32;
    __syncthreads();
    for (int idx = threadIdx.x; idx < 32 * IN_F; idx += 256) {
      int nl = idx >> 7, k = idx & 127;
      int n = n0 + nl;
      sx[k * 36 + nl] = (n < N_NODES) ? x[(size_t)n * IN_F + k] : 0.f;
    }
    __syncthreads();
    float a[8] = {bj, bj, bj, bj, bj, bj, bj, bj};
    const float* xp = &sx[ng * 8];
#pragma unroll 4
    for (int k = 0; k < IN_F; k++) {
      float4 h0 = *(const float4*)&xp[k * 36];
      float4 h1 = *(const float4*)&xp[k * 36 + 4];
      float w = sW[k * 64 + f];
      a[0] = fmaf(h0.x, w, a[0]); a[1] = fmaf(h0.y, w, a[1]);
      a[2] = fmaf(h0.z, w, a[2]); a[3] = fmaf(h0.w, w, a[3]);
      a[4] = fmaf(h1.x, w, a[4]); a[5] = fmaf(h1.y, w, a[5]);
      a[6] = fmaf(h1.z, w, a[6]); a[7] = fmaf(h1.w, w, a[7]);
    }
#pragma unroll
    for (int j = 0; j < 8; j++) {
      int n = n0 + ng * 8 + j;
      if (n < N_NODES) h[(size_t)n * 64 + f] = a[j];
    }
  }
}

// ------------------------------------------------------------------ pre A/B
// One TOWER per block (t = blockIdx.x & 1).  32-node groups, 8 nodes/thread.
// Weights packed interleaved: sWp[k*128 + f*2 + {0,1}] = {Wa[k,f], Wb[k,f]}
template <bool BN>
__global__ __launch_bounds__(256) void k_preab(const float* __restrict__ hin,
                                               const float* __restrict__ preW,
                                               const float* __restrict__ preb,
                                               const float* __restrict__ bnscale,
                                               const float* __restrict__ bnshift,
                                               float* __restrict__ h2out,
                                               float* __restrict__ hA,
                                               float* __restrict__ hB) {
  __shared__ float sWp[64 * 128];   // 32 KB packed [k][f][{A,B}]
  __shared__ float sh[64 * 36];     // h_T[k][32+pad4]  9216 B
  int t = blockIdx.x & 1;
  const float* Wsrc = preW + (size_t)t * 128 * 64;
  for (int i = threadIdx.x; i < 64 * 64; i += 256) {
    int k = i >> 6, f = i & 63;
    float wa = Wsrc[k * 64 + f];
    float wb = Wsrc[(64 + k) * 64 + f];
    *(float2*)&sWp[k * 128 + f * 2] = make_float2(wa, wb);
  }
  int f = threadIdx.x & 63, ng = threadIdx.x >> 6;   // ng 0..3 -> 8 nodes each
  float pb = preb[t * 64 + f];
  int nblk2 = gridDim.x >> 1;
  const int NGRP = (N_NODES + 31) / 32;   // 1563
  for (int grp = blockIdx.x >> 1; grp < NGRP; grp += nblk2) {
    int n0 = grp * 32;
    __syncthreads();
    for (int idx = threadIdx.x; idx < 32 * 64; idx += 256) {
      int nl = idx >> 6, k = idx & 63;
      int n = n0 + nl;
      float v = 0.f;
      if (n < N_NODES) {
        v = hin[(size_t)n * 64 + k];
        if (BN) {
          v = fmaxf(fmaf(v, bnscale[k], bnshift[k]), 0.f);
          if (t == 0) h2out[(size_t)n * 64 + k] = v;
        }
      }
      sh[k * 36 + nl] = v;
    }
    __syncthreads();
    float a[8] = {pb, pb, pb, pb, pb, pb, pb, pb};
    float b[8] = {0, 0, 0, 0, 0, 0, 0, 0};
    const float* hp = &sh[ng * 8];
    const float* wp = &sWp[f * 2];
#pragma unroll 4
    for (int k = 0; k < 64; k++) {
      float4 h0 = *(const float4*)&hp[k * 36];
      float4 h1 = *(const float4*)&hp[k * 36 + 4];
      float2 w2 = *(const float2*)&wp[k * 128];
      a[0] = fmaf(h0.x, w2.x, a[0]); b[0] = fmaf(h0.x, w2.y, b[0]);
      a[1] = fmaf(h0.y, w2.x, a[1]); b[1] = fmaf(h0.y, w2.y, b[1]);
      a[2] = fmaf(h0.z, w2.x, a[2]); b[2] = fmaf(h0.z, w2.y, b[2]);
      a[3] = fmaf(h0.w, w2.x, a[3]); b[3] = fmaf(h0.w, w2.y, b[3]);
      a[4] = fmaf(h1.x, w2.x, a[4]); b[4] = fmaf(h1.x, w2.y, b[4]);
      a[5] = fmaf(h1.y, w2.x, a[5]); b[5] = fmaf(h1.y, w2.y, b[5]);
      a[6] = fmaf(h1.z, w2.x, a[6]); b[6] = fmaf(h1.z, w2.y, b[6]);
      a[7] = fmaf(h1.w, w2.x, a[7]); b[7] = fmaf(h1.w, w2.y, b[7]);
    }
    int tf = t * 64 + f;
#pragma unroll
    for (int j = 0; j < 8; j++) {
      int n = n0 + ng * 8 + j;
      if (n < N_NODES) {
        hA[(size_t)n * 128 + tf] = a[j];
        hB[(size_t)n * 128 + tf] = b[j];
      }
    }
  }
}

// --------------------------------------------------- fused conv main kernel
// 8 nodes/block, 20.5 KB LDS, 7 blocks/CU.  Weights from PACKED transposed
// postWT: lane g reads dwordx4 = 4 consecutive-f13 weights (coalesced,
// 52 loads/thread instead of 208 scalar + 4x less address VALU).
__global__ __launch_bounds__(256, 7) void k_conv(const float* __restrict__ hA,
                                                 const float* __restrict__ hB,
                                                 const float* __restrict__ hskip,
                                                 const int* __restrict__ row_ptr,
                                                 const int* __restrict__ csr_src,
                                                 const float* __restrict__ postWT,
                                                 const float* __restrict__ postb,
                                                 const float* __restrict__ linWT,
                                                 const float* __restrict__ linb,
                                                 const float* __restrict__ scalars,
                                                 float* __restrict__ out) {
  __shared__ float sm[2 * 5 * 8 * 64];   // 20480 B; [(t*5+feat)*512 + node*64 + hf]
  __shared__ float sAB[16];              // sA[0..7], sB[8..15]
  int w = threadIdx.x >> 6, lane = threadIdx.x & 63;
  int n0 = blockIdx.x * 8;
  int t = lane >> 5, fb2 = (lane & 31) * 2;
  int off = t * 64 + fb2;
  float avg = scalars[1];

  // ---- phase A: aggregation, 2 nodes per wave, 4 loads in flight
#pragma unroll 1
  for (int k = 0; k < 2; k++) {
    int nl = w * 2 + k;
    int n = n0 + nl;
    float2 a = *(const float2*)&hA[(size_t)n * 128 + off];
    int rp0 = __builtin_amdgcn_readfirstlane(row_ptr[n]);
    int rp1 = __builtin_amdgcn_readfirstlane(row_ptr[n + 1]);
    float sx0=0,sy0=0,qx0=0,qy0=0, sx1=0,sy1=0,qx1=0,qy1=0;
    float mnx0=INFINITY,mny0=INFINITY,mxx0=-INFINITY,mxy0=-INFINITY;
    float mnx1=INFINITY,mny1=INFINITY,mxx1=-INFINITY,mxy1=-INFINITY;
    int i = rp0;
    int end4 = rp0 + ((rp1 - rp0) & ~3);
    if (i < end4) {
      int s0 = csr_src[i], s1 = csr_src[i+1], s2 = csr_src[i+2], s3 = csr_src[i+3];
      while (true) {
        float2 v0 = *(const float2*)&hB[(size_t)s0 * 128 + off];
        float2 v1 = *(const float2*)&hB[(size_t)s1 * 128 + off];
        float2 v2 = *(const float2*)&hB[(size_t)s2 * 128 + off];
        float2 v3 = *(const float2*)&hB[(size_t)s3 * 128 + off];
        i += 4;
        bool more = (i < end4);
        if (more) { s0 = csr_src[i]; s1 = csr_src[i+1]; s2 = csr_src[i+2]; s3 = csr_src[i+3]; }
        float e0x = v0.x + a.x, e0y = v0.y + a.y;
        float e1x = v1.x + a.x, e1y = v1.y + a.y;
        float e2x = v2.x + a.x, e2y = v2.y + a.y;
        float e3x = v3.x + a.x, e3y = v3.y + a.y;
        sx0 += e0x; qx0 = fmaf(e0x,e0x,qx0); mnx0 = fminf(mnx0,e0x); mxx0 = fmaxf(mxx0,e0x);
        sy0 += e0y; qy0 = fmaf(e0y,e0y,qy0); mny0 = fminf(mny0,e0y); mxy0 = fmaxf(mxy0,e0y);
        sx1 += e1x; qx1 = fmaf(e1x,e1x,qx1); mnx1 = fminf(mnx1,e1x); mxx1 = fmaxf(mxx1,e1x);
        sy1 += e1y; qy1 = fmaf(e1y,e1y,qy1); mny1 = fminf(mny1,e1y); mxy1 = fmaxf(mxy1,e1y);
        sx0 += e2x; qx0 = fmaf(e2x,e2x,qx0); mnx0 = fminf(mnx0,e2x); mxx0 = fmaxf(mxx0,e2x);
        sy0 += e2y; qy0 = fmaf(e2y,e2y,qy0); mny0 = fminf(mny0,e2y); mxy0 = fmaxf(mxy0,e2y);
        sx1 += e3x; qx1 = fmaf(e3x,e3x,qx1); mnx1 = fminf(mnx1,e3x); mxx1 = fmaxf(mxx1,e3x);
        sy1 += e3y; qy1 = fmaf(e3y,e3y,qy1); mny1 = fminf(mny1,e3y); mxy1 = fmaxf(mxy1,e3y);
        if (!more) break;
      }
    }
    {   // masked tail: 0..3 edges, all loads issued together
      int r = rp1 - i;
      if (r > 0) {
        int e1i = (r > 1) ? i + 1 : i;
        int e2i = (r > 2) ? i + 2 : i;
        int t0 = csr_src[i], t1 = csr_src[e1i], t2 = csr_src[e2i];
        float2 u0 = *(const float2*)&hB[(size_t)t0 * 128 + off];
        float2 u1 = *(const float2*)&hB[(size_t)t1 * 128 + off];
        float2 u2 = *(const float2*)&hB[(size_t)t2 * 128 + off];
        float ex = u0.x + a.x, ey = u0.y + a.y;
        sx0 += ex; qx0 = fmaf(ex,ex,qx0); mnx0 = fminf(mnx0,ex); mxx0 = fmaxf(mxx0,ex);
        sy0 += ey; qy0 = fmaf(ey,ey,qy0); mny0 = fminf(mny0,ey); mxy0 = fmaxf(mxy0,ey);
        if (r > 1) {
          ex = u1.x + a.x; ey = u1.y + a.y;
          sx1 += ex; qx1 = fmaf(ex,ex,qx1); mnx1 = fminf(mnx1,ex); mxx1 = fmaxf(mxx1,ex);
          sy1 += ey; qy1 = fmaf(ey,ey,qy1); mny1 = fminf(mny1,ey); mxy1 = fmaxf(mxy1,ey);
        }
        if (r > 2) {
          ex = u2.x + a.x; ey = u2.y + a.y;
          sx0 += ex; qx0 = fmaf(ex,ex,qx0); mnx0 = fminf(mnx0,ex); mxx0 = fmaxf(mxx0,ex);
          sy0 += ey; qy0 = fmaf(ey,ey,qy0); mny0 = fminf(mny0,ey); mxy0 = fmaxf(mxy0,ey);
        }
      }
    }
    int dg = rp1 - rp0;
    float cnt = (float)(dg > 0 ? dg : 1);
    float inv = 1.0f / cnt;
    float meanx = (sx0 + sx1) * inv, meany = (sy0 + sy1) * inv;
    float qx = qx0 + qx1, qy = qy0 + qy1;
    float sdx = sqrtf(fmaxf(qx * inv - meanx * meanx, 0.f) + STD_EPS);
    float sdy = sqrtf(fmaxf(qy * inv - meany * meany, 0.f) + STD_EPS);
    float mnx = fminf(mnx0, mnx1), mny = fminf(mny0, mny1);
    float mxx = fmaxf(mxx0, mxx1), mxy = fmaxf(mxy0, mxy1);
    if (dg == 0) { mnx = 0; mny = 0; mxx = 0; mxy = 0; }
    float ldv = logf(cnt + 1.f);
    float2 hsv = *(const float2*)&hskip[(size_t)n * 64 + fb2];
    // write 5 unique slices
    float* bp = &sm[t * 2560 + nl * 64 + fb2];
    *(float2*)&bp[0]    = hsv;
    *(float2*)&bp[512]  = make_float2(meanx, meany);
    *(float2*)&bp[1024] = make_float2(mnx, mny);
    *(float2*)&bp[1536] = make_float2(mxx, mxy);
    *(float2*)&bp[2048] = make_float2(sdx, sdy);
    if (lane == 0) { sAB[nl] = ldv / avg; sAB[8 + nl] = avg / ldv; }
  }
  __syncthreads();

  // ---- phase C: factored post matmul; wave w covers hf [w*16, w*16+16)
  float g1[8] = {0,0,0,0,0,0,0,0};
  float g2[8] = {0,0,0,0,0,0,0,0};
  float g3[8] = {0,0,0,0,0,0,0,0};
  {
    int g = lane & 31, hf0 = w * 16, fb0 = w * 4;
    // pw4[fb*32] = float4 of weights (f13=fb*4..+3) for col g of tower t
    const float4* pw4 = (const float4*)postWT + (size_t)t * 6656 + g;
    const float* vb = &sm[t * 2560 + hf0];
    // feat0 = h: G1 only
#pragma unroll
    for (int jj = 0; jj < 4; jj++) {
      float4 wv = pw4[(fb0 + jj) * 32];
#pragma unroll
      for (int nn = 0; nn < 8; nn++) {
        float4 v = *(const float4*)&vb[nn * 64 + jj * 4];
        g1[nn] = fmaf(v.w, wv.w, fmaf(v.z, wv.z, fmaf(v.y, wv.y, fmaf(v.x, wv.x, g1[nn]))));
      }
    }
    // feats 1..4 (agg): fb = 16+fa*16+fb0+jj; G2 at +64 fb, G3 at +128 fb
#pragma unroll
    for (int fa = 0; fa < 4; fa++) {
      const float* vfa = &vb[(1 + fa) * 512];
#pragma unroll
      for (int jj = 0; jj < 4; jj++) {
        int fb = 16 + fa * 16 + fb0 + jj;
        float4 w1v = pw4[fb * 32];
        float4 w2v = pw4[(fb + 64) * 32];
        float4 w3v = pw4[(fb + 128) * 32];
#pragma unroll
        for (int nn = 0; nn < 8; nn++) {
          float4 v = *(const float4*)&vfa[nn * 64 + jj * 4];
          g1[nn] = fmaf(v.w, w1v.w, fmaf(v.z, w1v.z, fmaf(v.y, w1v.y, fmaf(v.x, w1v.x, g1[nn]))));
          g2[nn] = fmaf(v.w, w2v.w, fmaf(v.z, w2v.z, fmaf(v.y, w2v.y, fmaf(v.x, w2v.x, g2[nn]))));
          g3[nn] = fmaf(v.w, w3v.w, fmaf(v.z, w3v.z, fmaf(v.y, w3v.y, fmaf(v.x, w3v.x, g3[nn]))));
        }
      }
    }
  }
  // combine with per-node scalars (sAB reads are broadcast)
  float o8[8];
#pragma unroll
  for (int nn = 0; nn < 8; nn++)
    o8[nn] = fmaf(sAB[8 + nn], g3[nn], fmaf(sAB[nn], g2[nn], g1[nn]));
  __syncthreads();   // all sm reads done -> safe to alias

  // ---- partials into aliased region: lpart[node8][tg64][rep4] = sm[0..2047]
  {
    int sw = (w + (lane >> 4)) & 3;
#pragma unroll
    for (int nn = 0; nn < 8; nn++)
      sm[((nn * 64 + lane) << 2) + sw] = o8[nn];
  }
  __syncthreads();

  // ---- reduce + postb -> po at sm[2048 + node*64 + col]
  {
#pragma unroll
    for (int r = 0; r < 2; r++) {
      int idx = r * 256 + (int)threadIdx.x;
      float4 p = *(const float4*)&sm[idx << 2];
      sm[2048 + idx] = p.x + p.y + p.z + p.w + postb[idx & 63];
    }
  }
  __syncthreads();

  // ---- lin epilogue: wave w -> nodes w*2, w*2+1; col = lane
  // linWT packed: lw4[c4*64] = float4 of rows 4c4..+3 for col=lane (coalesced)
  {
    float acc0 = linb[lane], acc1 = acc0;
    const float4* lw4 = (const float4*)linWT + lane;
    const float* p0 = &sm[2048 + (w * 2) * 64];
    const float* p1 = p0 + 64;
#pragma unroll
    for (int c4 = 0; c4 < 16; c4++) {
      float4 lwv = lw4[c4 * 64];
      float4 pa = *(const float4*)&p0[c4 * 4];
      float4 pb2 = *(const float4*)&p1[c4 * 4];
      acc0 = fmaf(pa.w, lwv.w, fmaf(pa.z, lwv.z, fmaf(pa.y, lwv.y, fmaf(pa.x, lwv.x, acc0))));
      acc1 = fmaf(pb2.w, lwv.w, fmaf(pb2.z, lwv.z, fmaf(pb2.y, lwv.y, fmaf(pb2.x, lwv.x, acc1))));
    }
    size_t ob = (size_t)(n0 + w * 2) * 64 + lane;
    out[ob] = acc0;
    out[ob + 64] = acc1;
  }
}

// ------------------------------------------------------------------ BN stats
__global__ __launch_bounds__(256) void k_bnstats(const float* __restrict__ y,
                                                 float* __restrict__ bnsum,
                                                 float* __restrict__ bnsumsq) {
  __shared__ float r1[256], r2[256];
  int c = threadIdx.x & 63, r = threadIdx.x >> 6;
  float s = 0, q = 0;
  for (int n = blockIdx.x * 4 + r; n < N_NODES; n += gridDim.x * 4) {
    float v = y[(size_t)n * 64 + c];
    s += v; q = fmaf(v, v, q);
  }
  r1[threadIdx.x] = s; r2[threadIdx.x] = q; __syncthreads();
  if (threadIdx.x < 64) {
    s = r1[threadIdx.x] + r1[threadIdx.x + 64] + r1[threadIdx.x + 128] + r1[threadIdx.x + 192];
    q = r2[threadIdx.x] + r2[threadIdx.x + 64] + r2[threadIdx.x + 128] + r2[threadIdx.x + 192];
    atomicAdd(&bnsum[threadIdx.x], s);
    atomicAdd(&bnsumsq[threadIdx.x], q);
  }
}

__global__ void k_bnfin(const float* __restrict__ bnsum, const float* __restrict__ bnsumsq,
                        const float* __restrict__ gamma, const float* __restrict__ beta,
                        float* __restrict__ bnscale, float* __restrict__ bnshift) {
  int c = threadIdx.x;
  if (c < 64) {
    float mu = bnsum[c] * (1.f / N_NODES);
    float var = bnsumsq[c] * (1.f / N_NODES) - mu * mu;
    float sc = gamma[c] / sqrtf(var + BN_EPS);
    bnscale[c] = sc;
    bnshift[c] = fmaf(-mu, sc, beta[c]);
  }
}

// ================================================================== launcher
extern "C" void kernel_launch(void* const* d_in, const int* in_sizes, int n_in,
                              void* d_out, int out_size, void* d_ws, size_t ws_size,
                              hipStream_t stream) {
  const float* x      = (const float*)d_in[0];
  const float* embW   = (const float*)d_in[1];
  const float* embB   = (const float*)d_in[2];
  const float* preW1  = (const float*)d_in[3];
  const float* preb1  = (const float*)d_in[4];
  const float* postW1 = (const float*)d_in[5];
  const float* postb1 = (const float*)d_in[6];
  const float* linW1  = (const float*)d_in[7];
  const float* linb1  = (const float*)d_in[8];
  const float* gamma  = (const float*)d_in[9];
  const float* beta   = (const float*)d_in[10];
  const float* preW2  = (const float*)d_in[11];
  const float* preb2  = (const float*)d_in[12];
  const float* postW2 = (const float*)d_in[13];
  const float* postb2 = (const float*)d_in[14];
  const float* linW2  = (const float*)d_in[15];
  const float* linb2  = (const float*)d_in[16];
  const int*   src    = (const int*)d_in[17];
  const int*   dst    = (const int*)d_in[18];
  float* out = (float*)d_out;

  char* w = (char*)d_ws;
  size_t o = 0;
  int*   deg     = (int*)(w + o);   o += (size_t)N_NODES * 4;
  float* scalars = (float*)(w + o); o += 64;
  float* bnsum   = (float*)(w + o); o += 256;
  float* bnsumsq = (float*)(w + o); o += 256;
  float* bnscale = (float*)(w + o); o += 256;
  float* bnshift = (float*)(w + o); o += 256;
  size_t zero_len = o;
  o = (o + 255) & ~(size_t)255;
  int* partials = (int*)(w + o);  o += 256;
  int* row_ptr  = (int*)(w + o);  o += (size_t)(N_NODES + 1) * 4; o = (o + 255) & ~(size_t)255;
  int* cursor   = (int*)(w + o);  o += (size_t)N_NODES * 4;       o = (o + 255) & ~(size_t)255;
  int* csr      = (int*)(w + o);  o += (size_t)E_EDGES * 4;       o = (o + 255) & ~(size_t)255;
  float* postWT = (float*)(w + o); o += (size_t)2 * 53248 * 4;
  float* linWT  = (float*)(w + o); o += (size_t)2 * 4096 * 4;
  float* h1 = (float*)(w + o); o += (size_t)N_NODES * 64 * 4;
  float* y1 = (float*)(w + o); o += (size_t)N_NODES * 64 * 4;
  float* h2 = (float*)(w + o); o += (size_t)N_NODES * 64 * 4;
  float* hA = (float*)(w + o); o += (size_t)N_NODES * 128 * 4;
  float* hB = (float*)(w + o); o += (size_t)N_NODES * 128 * 4;

  hipMemsetAsync(w, 0, zero_len, stream);

  const int NBLK_SCAN = (N_NODES + 1023) / 1024;   // 49
  k_hist<<<(E_EDGES + 255) / 256, 256, 0, stream>>>(dst, deg);
  k_scan_part<<<NBLK_SCAN, 256, 0, stream>>>(deg, partials, scalars);
  k_scan_mid<<<1, 64, 0, stream>>>(partials, NBLK_SCAN, scalars);
  k_scan_final<<<NBLK_SCAN, 256, 0, stream>>>(deg, partials, row_ptr, cursor);
  k_scatter<<<(E_EDGES + 255) / 256, 256, 0, stream>>>(src, dst, cursor, csr);
  k_transpose<<<448, 256, 0, stream>>>(postW1, postW2, linW1, linW2, postWT, linWT);

  k_embed<<<768, 256, 0, stream>>>(x, embW, embB, h1);

  // ----- layer 1
  k_preab<false><<<768, 256, 0, stream>>>(h1, preW1, preb1, nullptr, nullptr, nullptr, hA, hB);
  k_conv<<<N_NODES / 8, 256, 0, stream>>>(hA, hB, h1, row_ptr, csr,
                                          postWT, postb1, linWT, linb1, scalars, y1);
  // ----- batchnorm
  k_bnstats<<<256, 256, 0, stream>>>(y1, bnsum, bnsumsq);
  k_bnfin<<<1, 64, 0, stream>>>(bnsum, bnsumsq, gamma, beta, bnscale, bnshift);

  // ----- layer 2 (BN+relu fused into staging; h2 materialized for skip)
  k_preab<true><<<768, 256, 0, stream>>>(y1, preW2, preb2, bnscale, bnshift, h2, hA, hB);
  k_conv<<<N_NODES / 8, 256, 0, stream>>>(hA, hB, h2, row_ptr, csr,
                                          postWT + 53248, postb2, linWT + 4096, linb2,
                                          scalars, out);
}